// Round 1
// baseline (1798.298 us; speedup 1.0000x reference)
//
#include <hip/hip_runtime.h>
#include <math.h>

#define NN 100000
#define NE 1000000
#define IND 256
#define HD  128
#define NPB 32           // nodes per block in GEMM-ish kernels
#define NBLK_SCAN 98     // ceil(NN/1024)

// ---------------- CSR build ----------------

__global__ __launch_bounds__(256) void k_deg(const int* __restrict__ dst,
                                             int* __restrict__ deg) {
    int e = blockIdx.x * 256 + threadIdx.x;
    if (e < NE) atomicAdd(&deg[dst[e]], 1);
}

__global__ __launch_bounds__(256) void k_dinv(const int* __restrict__ deg,
                                              float* __restrict__ dinv) {
    int i = blockIdx.x * 256 + threadIdx.x;
    if (i < NN) dinv[i] = rsqrtf((float)(deg[i] + 1));  // +1 self-loop
}

__global__ __launch_bounds__(1024) void k_scan1(const int* __restrict__ deg,
                                                int* __restrict__ rowp,
                                                int* __restrict__ bsums) {
    __shared__ int s[1024];
    int t = threadIdx.x;
    int i = blockIdx.x * 1024 + t;
    int v = (i < NN) ? deg[i] : 0;
    s[t] = v;
    __syncthreads();
    for (int off = 1; off < 1024; off <<= 1) {
        int u = (t >= off) ? s[t - off] : 0;
        __syncthreads();
        s[t] += u;
        __syncthreads();
    }
    if (i < NN) rowp[i] = s[t] - v;           // exclusive within block
    if (t == 1023) bsums[blockIdx.x] = s[1023];
}

__global__ __launch_bounds__(128) void k_scan2(int* __restrict__ bsums) {
    __shared__ int s[128];
    int t = threadIdx.x;
    int v = (t < NBLK_SCAN) ? bsums[t] : 0;
    s[t] = v;
    __syncthreads();
    for (int off = 1; off < 128; off <<= 1) {
        int u = (t >= off) ? s[t - off] : 0;
        __syncthreads();
        s[t] += u;
        __syncthreads();
    }
    if (t < NBLK_SCAN) bsums[t] = s[t] - v;   // exclusive
}

__global__ __launch_bounds__(1024) void k_scan3(int* __restrict__ rowp,
                                                const int* __restrict__ bsums) {
    int i = blockIdx.x * 1024 + threadIdx.x;
    if (i < NN) rowp[i] += bsums[i >> 10];
    if (i == 0) rowp[NN] = NE;
}

__global__ __launch_bounds__(256) void k_fill(const int* __restrict__ src,
                                              const int* __restrict__ dst,
                                              const int* __restrict__ rowp,
                                              int* __restrict__ fill,
                                              int* __restrict__ col) {
    int e = blockIdx.x * 256 + threadIdx.x;
    if (e < NE) {
        int d = dst[e];
        int pos = rowp[d] + atomicAdd(&fill[d], 1);
        col[pos] = src[e];
    }
}

// ---------------- initial transform: h0 = relu(x@W1+b1), g0 = dinv*h0 ----------------

__global__ __launch_bounds__(256) void k_init(const float* __restrict__ x,
                                              const float* __restrict__ W1,
                                              const float* __restrict__ b1,
                                              const float* __restrict__ dinv,
                                              float* __restrict__ h0,
                                              float* __restrict__ g0) {
    __shared__ float xs[NPB * IND];  // 32 KB
    int tid = threadIdx.x;
    int nb = blockIdx.x * NPB;

    // stage x rows
    const float* xg = x + (size_t)nb * IND;
    for (int idx = tid * 4; idx < NPB * IND; idx += 256 * 4)
        *(float4*)&xs[idx] = *(const float4*)&xg[idx];
    __syncthreads();

    int jb = tid & 31, ng = tid >> 5;
    int j0 = jb * 4;
    float acc[4][4];
#pragma unroll
    for (int n = 0; n < 4; n++)
#pragma unroll
        for (int jj = 0; jj < 4; jj++) acc[n][jj] = 0.f;

    for (int kk = 0; kk < IND / 4; kk++) {
        float w[4][4];
#pragma unroll
        for (int q = 0; q < 4; q++) {
            float4 wv = *(const float4*)&W1[(kk * 4 + q) * HD + j0];
            w[q][0] = wv.x; w[q][1] = wv.y; w[q][2] = wv.z; w[q][3] = wv.w;
        }
#pragma unroll
        for (int n = 0; n < 4; n++) {
            float4 c = *(const float4*)&xs[(ng * 4 + n) * IND + kk * 4];
#pragma unroll
            for (int jj = 0; jj < 4; jj++)
                acc[n][jj] = fmaf(c.x, w[0][jj],
                            fmaf(c.y, w[1][jj],
                            fmaf(c.z, w[2][jj],
                            fmaf(c.w, w[3][jj], acc[n][jj]))));
        }
    }

#pragma unroll
    for (int n = 0; n < 4; n++) {
        int gn = nb + ng * 4 + n;
        float dv = dinv[gn];
        float4 hv, gv;
        float* hp = (float*)&hv; float* gp = (float*)&gv;
#pragma unroll
        for (int jj = 0; jj < 4; jj++) {
            float v = acc[n][jj] + b1[j0 + jj];
            v = v > 0.f ? v : 0.f;
            hp[jj] = v;
            gp[jj] = dv * v;
        }
        *(float4*)&h0[(size_t)gn * HD + j0] = hv;
        *(float4*)&g0[(size_t)gn * HD + j0] = gv;
    }
}

// ---------------- GCNII layer: gather + residual + GEMM, writes g_out = dinv*h_new ----------------

__global__ __launch_bounds__(256) void k_layer(const float* __restrict__ gIn,
                                               float* __restrict__ gOut,
                                               const float* __restrict__ h0,
                                               const float* __restrict__ dinv,
                                               const int* __restrict__ rowp,
                                               const int* __restrict__ col,
                                               const float* __restrict__ W,
                                               float beta) {
    __shared__ float cs[NPB * HD];  // 16 KB: comb rows
    int tid = threadIdx.x;
    int nb = blockIdx.x * NPB;
    int wave = tid >> 6, lane = tid & 63;

    // gather phase: one wave per node, lane covers 2 features
    for (int nl = wave; nl < NPB; nl += 4) {
        int n = nb + nl;
        float2 sum = *(const float2*)&gIn[(size_t)n * HD + lane * 2];  // self-loop
        int beg = rowp[n], end = rowp[n + 1];
        for (int e = beg; e < end; e++) {
            int s = col[e];
            float2 gv = *(const float2*)&gIn[(size_t)s * HD + lane * 2];
            sum.x += gv.x; sum.y += gv.y;
        }
        float dv = dinv[n];
        float2 hv = *(const float2*)&h0[(size_t)n * HD + lane * 2];
        float2 cb;
        cb.x = 0.9f * dv * sum.x + 0.1f * hv.x;
        cb.y = 0.9f * dv * sum.y + 0.1f * hv.y;
        *(float2*)&cs[nl * HD + lane * 2] = cb;
    }
    __syncthreads();

    // GEMM phase: h = relu((1-b)*comb + b*comb@W); g_out = dinv*h
    int jb = tid & 31, ng = tid >> 5;
    int j0 = jb * 4;
    float acc[4][4];
#pragma unroll
    for (int n = 0; n < 4; n++)
#pragma unroll
        for (int jj = 0; jj < 4; jj++) acc[n][jj] = 0.f;

    for (int kk = 0; kk < HD / 4; kk++) {
        float w[4][4];
#pragma unroll
        for (int q = 0; q < 4; q++) {
            float4 wv = *(const float4*)&W[(kk * 4 + q) * HD + j0];
            w[q][0] = wv.x; w[q][1] = wv.y; w[q][2] = wv.z; w[q][3] = wv.w;
        }
#pragma unroll
        for (int n = 0; n < 4; n++) {
            float4 c = *(const float4*)&cs[(ng * 4 + n) * HD + kk * 4];
#pragma unroll
            for (int jj = 0; jj < 4; jj++)
                acc[n][jj] = fmaf(c.x, w[0][jj],
                            fmaf(c.y, w[1][jj],
                            fmaf(c.z, w[2][jj],
                            fmaf(c.w, w[3][jj], acc[n][jj]))));
        }
    }

    float omb = 1.f - beta;
#pragma unroll
    for (int n = 0; n < 4; n++) {
        int gn = nb + ng * 4 + n;
        float dv = dinv[gn];
        float4 cb = *(const float4*)&cs[(ng * 4 + n) * HD + j0];
        float* cp = (float*)&cb;
        float4 ov; float* op = (float*)&ov;
#pragma unroll
        for (int jj = 0; jj < 4; jj++) {
            float v = omb * cp[jj] + beta * acc[n][jj];
            v = v > 0.f ? v : 0.f;
            op[jj] = dv * v;
        }
        *(float4*)&gOut[(size_t)gn * HD + j0] = ov;
    }
}

// ---------------- final: out = h@W2+b2; vis = relu(out@Wv+bv); text = relu(out@Wt+bt) ----------------

__global__ __launch_bounds__(256) void k_final(const float* __restrict__ g,
                                               const int* __restrict__ deg,
                                               const float* __restrict__ W2,
                                               const float* __restrict__ b2,
                                               const float* __restrict__ Wv,
                                               const float* __restrict__ bv,
                                               const float* __restrict__ Wt,
                                               const float* __restrict__ bt,
                                               float* __restrict__ out,
                                               float* __restrict__ vis,
                                               float* __restrict__ txt) {
    __shared__ float hs[NPB * HD];  // h rows
    __shared__ float os[NPB * HD];  // out rows
    int tid = threadIdx.x;
    int nb = blockIdx.x * NPB;

    // stage h = g * sqrt(deg+1)
    for (int idx = tid * 4; idx < NPB * HD; idx += 256 * 4) {
        int row = idx >> 7;
        float sq = sqrtf((float)(deg[nb + row] + 1));
        float4 gv = *(const float4*)&g[(size_t)nb * HD + idx];
        gv.x *= sq; gv.y *= sq; gv.z *= sq; gv.w *= sq;
        *(float4*)&hs[idx] = gv;
    }
    __syncthreads();

    int jb = tid & 31, ng = tid >> 5;
    int j0 = jb * 4;

    // out = h@W2 + b2 (no relu)
    {
        float acc[4][4];
#pragma unroll
        for (int n = 0; n < 4; n++)
#pragma unroll
            for (int jj = 0; jj < 4; jj++) acc[n][jj] = 0.f;
        for (int kk = 0; kk < HD / 4; kk++) {
            float w[4][4];
#pragma unroll
            for (int q = 0; q < 4; q++) {
                float4 wv = *(const float4*)&W2[(kk * 4 + q) * HD + j0];
                w[q][0] = wv.x; w[q][1] = wv.y; w[q][2] = wv.z; w[q][3] = wv.w;
            }
#pragma unroll
            for (int n = 0; n < 4; n++) {
                float4 c = *(const float4*)&hs[(ng * 4 + n) * HD + kk * 4];
#pragma unroll
                for (int jj = 0; jj < 4; jj++)
                    acc[n][jj] = fmaf(c.x, w[0][jj],
                                fmaf(c.y, w[1][jj],
                                fmaf(c.z, w[2][jj],
                                fmaf(c.w, w[3][jj], acc[n][jj]))));
            }
        }
#pragma unroll
        for (int n = 0; n < 4; n++) {
            int gn = nb + ng * 4 + n;
            float4 ov; float* op = (float*)&ov;
#pragma unroll
            for (int jj = 0; jj < 4; jj++) op[jj] = acc[n][jj] + b2[j0 + jj];
            *(float4*)&out[(size_t)gn * HD + j0] = ov;
            *(float4*)&os[(ng * 4 + n) * HD + j0] = ov;
        }
    }
    __syncthreads();

    // vis and txt from os
    const float* Ws[2] = {Wv, Wt};
    const float* bs[2] = {bv, bt};
    float* outs[2] = {vis, txt};
#pragma unroll
    for (int m = 0; m < 2; m++) {
        const float* Wm = Ws[m];
        const float* bm = bs[m];
        float* om = outs[m];
        float acc[4][4];
#pragma unroll
        for (int n = 0; n < 4; n++)
#pragma unroll
            for (int jj = 0; jj < 4; jj++) acc[n][jj] = 0.f;
        for (int kk = 0; kk < HD / 4; kk++) {
            float w[4][4];
#pragma unroll
            for (int q = 0; q < 4; q++) {
                float4 wv = *(const float4*)&Wm[(kk * 4 + q) * HD + j0];
                w[q][0] = wv.x; w[q][1] = wv.y; w[q][2] = wv.z; w[q][3] = wv.w;
            }
#pragma unroll
            for (int n = 0; n < 4; n++) {
                float4 c = *(const float4*)&os[(ng * 4 + n) * HD + kk * 4];
#pragma unroll
                for (int jj = 0; jj < 4; jj++)
                    acc[n][jj] = fmaf(c.x, w[0][jj],
                                fmaf(c.y, w[1][jj],
                                fmaf(c.z, w[2][jj],
                                fmaf(c.w, w[3][jj], acc[n][jj]))));
            }
        }
#pragma unroll
        for (int n = 0; n < 4; n++) {
            int gn = nb + ng * 4 + n;
            float4 ov; float* op = (float*)&ov;
#pragma unroll
            for (int jj = 0; jj < 4; jj++) {
                float v = acc[n][jj] + bm[j0 + jj];
                op[jj] = v > 0.f ? v : 0.f;
            }
            *(float4*)&om[(size_t)gn * HD + j0] = ov;
        }
    }
}

// ---------------- launch ----------------

extern "C" void kernel_launch(void* const* d_in, const int* in_sizes, int n_in,
                              void* d_out, int out_size, void* d_ws, size_t ws_size,
                              hipStream_t stream) {
    (void)in_sizes; (void)n_in; (void)out_size; (void)ws_size;

    const float* x    = (const float*)d_in[0];
    const int*   edge = (const int*)d_in[1];   // [2,E]: src then dst
    const float* W1   = (const float*)d_in[2];
    const float* b1   = (const float*)d_in[3];
    const float* cw   = (const float*)d_in[4]; // [8,128,128]
    const float* W2   = (const float*)d_in[5];
    const float* b2   = (const float*)d_in[6];
    const float* Wv   = (const float*)d_in[7];
    const float* bv   = (const float*)d_in[8];
    const float* Wt   = (const float*)d_in[9];
    const float* bt   = (const float*)d_in[10];

    const int* esrc = edge;
    const int* edst = edge + NE;

    // d_out regions double as scratch: [0]=h0 then out, [1]/[2] = g ping-pong
    float* out0 = (float*)d_out;
    float* reg1 = out0 + (size_t)NN * HD;
    float* reg2 = reg1 + (size_t)NN * HD;

    // workspace layout
    char* ws = (char*)d_ws;
    int*   deg_i = (int*)(ws + 0);          // N ints
    int*   fill  = (int*)(ws + 400000);     // N ints
    int*   rowp  = (int*)(ws + 800000);     // N+1 ints
    int*   bsums = (int*)(ws + 1200128);    // 128 ints
    int*   col   = (int*)(ws + 1200640);    // E ints
    float* dinv  = (float*)(ws + 5200640);  // N floats

    hipMemsetAsync(ws, 0, 800000, stream);  // deg_i + fill

    k_deg<<<(NE + 255) / 256, 256, 0, stream>>>(edst, deg_i);
    k_dinv<<<(NN + 255) / 256, 256, 0, stream>>>(deg_i, dinv);
    k_scan1<<<NBLK_SCAN, 1024, 0, stream>>>(deg_i, rowp, bsums);
    k_scan2<<<1, 128, 0, stream>>>(bsums);
    k_scan3<<<NBLK_SCAN, 1024, 0, stream>>>(rowp, bsums);
    k_fill<<<(NE + 255) / 256, 256, 0, stream>>>(esrc, edst, rowp, fill, col);

    // h0 -> out0 region, g0 -> reg1
    k_init<<<NN / NPB, 256, 0, stream>>>(x, W1, b1, dinv, out0, reg1);

    for (int l = 0; l < 8; l++) {
        float beta = (float)log(0.5 / (double)(l + 1) + 1.0);
        const float* gi = (l & 1) ? reg2 : reg1;
        float*       go = (l & 1) ? reg1 : reg2;
        k_layer<<<NN / NPB, 256, 0, stream>>>(gi, go, out0, dinv, rowp, col,
                                              cw + (size_t)l * HD * HD, beta);
    }
    // after 8 layers, g is in reg1

    k_final<<<NN / NPB, 256, 0, stream>>>(reg1, deg_i, W2, b2, Wv, bv, Wt, bt,
                                          out0, reg1, reg2);
}

// Round 2
// 1266.813 us; speedup vs baseline: 1.4195x; 1.4195x over previous
//
#include <hip/hip_runtime.h>
#include <hip/hip_fp16.h>
#include <math.h>

#define NN 100000
#define NE 1000000
#define IND 256
#define HD  128
#define HD2 64           // half2 elements per row
#define NPB 32           // nodes per block in GEMM-ish kernels
#define NBLK_SCAN 98     // ceil(NN/1024)
#define H16_BYTES ((size_t)NN * HD * 2)   // 25,600,000

// ---------------- CSR build ----------------

__global__ __launch_bounds__(256) void k_deg(const int* __restrict__ dst,
                                             int* __restrict__ deg) {
    int e = blockIdx.x * 256 + threadIdx.x;
    if (e < NE) atomicAdd(&deg[dst[e]], 1);
}

__global__ __launch_bounds__(256) void k_dinv(const int* __restrict__ deg,
                                              float* __restrict__ dinv) {
    int i = blockIdx.x * 256 + threadIdx.x;
    if (i < NN) dinv[i] = rsqrtf((float)(deg[i] + 1));  // +1 self-loop
}

__global__ __launch_bounds__(1024) void k_scan1(const int* __restrict__ deg,
                                                int* __restrict__ rowp,
                                                int* __restrict__ bsums) {
    __shared__ int s[1024];
    int t = threadIdx.x;
    int i = blockIdx.x * 1024 + t;
    int v = (i < NN) ? deg[i] : 0;
    s[t] = v;
    __syncthreads();
    for (int off = 1; off < 1024; off <<= 1) {
        int u = (t >= off) ? s[t - off] : 0;
        __syncthreads();
        s[t] += u;
        __syncthreads();
    }
    if (i < NN) rowp[i] = s[t] - v;           // exclusive within block
    if (t == 1023) bsums[blockIdx.x] = s[1023];
}

__global__ __launch_bounds__(128) void k_scan2(int* __restrict__ bsums) {
    __shared__ int s[128];
    int t = threadIdx.x;
    int v = (t < NBLK_SCAN) ? bsums[t] : 0;
    s[t] = v;
    __syncthreads();
    for (int off = 1; off < 128; off <<= 1) {
        int u = (t >= off) ? s[t - off] : 0;
        __syncthreads();
        s[t] += u;
        __syncthreads();
    }
    if (t < NBLK_SCAN) bsums[t] = s[t] - v;   // exclusive
}

__global__ __launch_bounds__(1024) void k_scan3(int* __restrict__ rowp,
                                                const int* __restrict__ bsums) {
    int i = blockIdx.x * 1024 + threadIdx.x;
    if (i < NN) rowp[i] += bsums[i >> 10];
    if (i == 0) rowp[NN] = NE;
}

__global__ __launch_bounds__(256) void k_fill(const int* __restrict__ src,
                                              const int* __restrict__ dst,
                                              const int* __restrict__ rowp,
                                              int* __restrict__ fill,
                                              int* __restrict__ col) {
    int e = blockIdx.x * 256 + threadIdx.x;
    if (e < NE) {
        int d = dst[e];
        int pos = rowp[d] + atomicAdd(&fill[d], 1);
        col[pos] = src[e];
    }
}

// ---------------- initial transform: h0 = relu(x@W1+b1) (f16), g0 = dinv*h0 (f16) ----

__global__ __launch_bounds__(256) void k_init(const float* __restrict__ x,
                                              const float* __restrict__ W1,
                                              const float* __restrict__ b1,
                                              const float* __restrict__ dinv,
                                              __half2* __restrict__ h0h,
                                              __half2* __restrict__ g0) {
    __shared__ float xs[NPB * IND];  // 32 KB
    int tid = threadIdx.x;
    int nb = blockIdx.x * NPB;

    const float* xg = x + (size_t)nb * IND;
    for (int idx = tid * 4; idx < NPB * IND; idx += 256 * 4)
        *(float4*)&xs[idx] = *(const float4*)&xg[idx];
    __syncthreads();

    int jb = tid & 31, ng = tid >> 5;
    int j0 = jb * 4;
    float acc[4][4];
#pragma unroll
    for (int n = 0; n < 4; n++)
#pragma unroll
        for (int jj = 0; jj < 4; jj++) acc[n][jj] = 0.f;

    for (int kk = 0; kk < IND / 4; kk++) {
        float w[4][4];
#pragma unroll
        for (int q = 0; q < 4; q++) {
            float4 wv = *(const float4*)&W1[(kk * 4 + q) * HD + j0];
            w[q][0] = wv.x; w[q][1] = wv.y; w[q][2] = wv.z; w[q][3] = wv.w;
        }
#pragma unroll
        for (int n = 0; n < 4; n++) {
            float4 c = *(const float4*)&xs[(ng * 4 + n) * IND + kk * 4];
#pragma unroll
            for (int jj = 0; jj < 4; jj++)
                acc[n][jj] = fmaf(c.x, w[0][jj],
                            fmaf(c.y, w[1][jj],
                            fmaf(c.z, w[2][jj],
                            fmaf(c.w, w[3][jj], acc[n][jj]))));
        }
    }

#pragma unroll
    for (int n = 0; n < 4; n++) {
        int gn = nb + ng * 4 + n;
        float dv = dinv[gn];
        float2 h01, h23, g01, g23;
        float v0 = fmaxf(acc[n][0] + b1[j0 + 0], 0.f);
        float v1 = fmaxf(acc[n][1] + b1[j0 + 1], 0.f);
        float v2 = fmaxf(acc[n][2] + b1[j0 + 2], 0.f);
        float v3 = fmaxf(acc[n][3] + b1[j0 + 3], 0.f);
        h01 = make_float2(v0, v1); h23 = make_float2(v2, v3);
        g01 = make_float2(dv * v0, dv * v1); g23 = make_float2(dv * v2, dv * v3);
        size_t base = (size_t)gn * HD2 + (j0 >> 1);
        h0h[base]     = __float22half2_rn(h01);
        h0h[base + 1] = __float22half2_rn(h23);
        g0[base]      = __float22half2_rn(g01);
        g0[base + 1]  = __float22half2_rn(g23);
    }
}

// ---------------- GCNII layer ----------------
// OUT_MODE 0: gOut = f16(dinv*h)   OUT_MODE 1: hOut = f32 h (last layer)

template <int OUT_MODE>
__global__ __launch_bounds__(256) void k_layer(const __half2* __restrict__ gIn,
                                               __half2* __restrict__ gOut,
                                               float* __restrict__ hOut,
                                               const __half2* __restrict__ h0,
                                               const float* __restrict__ dinv,
                                               const int* __restrict__ rowp,
                                               const int* __restrict__ col,
                                               const float* __restrict__ W,
                                               float beta) {
    __shared__ float cs[NPB * HD];  // 16 KB: comb rows
    int tid = threadIdx.x;
    int nb = blockIdx.x * NPB;
    int wave = tid >> 6, lane = tid & 63;

    // gather phase: one wave per node, lane covers 2 features (one half2)
    for (int nl = wave; nl < NPB; nl += 4) {
        int n = nb + nl;
        float2 sum;
        {
            float2 s0 = __half22float2(gIn[(size_t)n * HD2 + lane]);  // self-loop
            sum = s0;
        }
        int beg = rowp[n], end = rowp[n + 1];
        int e = beg;
        for (; e + 4 <= end; e += 4) {
            int s0 = col[e], s1 = col[e + 1], s2 = col[e + 2], s3 = col[e + 3];
            __half2 a0 = gIn[(size_t)s0 * HD2 + lane];
            __half2 a1 = gIn[(size_t)s1 * HD2 + lane];
            __half2 a2 = gIn[(size_t)s2 * HD2 + lane];
            __half2 a3 = gIn[(size_t)s3 * HD2 + lane];
            float2 f0 = __half22float2(a0), f1 = __half22float2(a1);
            float2 f2 = __half22float2(a2), f3 = __half22float2(a3);
            float tx01 = f0.x + f1.x, ty01 = f0.y + f1.y;
            float tx23 = f2.x + f3.x, ty23 = f2.y + f3.y;
            sum.x += tx01 + tx23; sum.y += ty01 + ty23;
        }
        for (; e < end; e++) {
            float2 f = __half22float2(gIn[(size_t)col[e] * HD2 + lane]);
            sum.x += f.x; sum.y += f.y;
        }
        float dv = dinv[n];
        float2 hv = __half22float2(h0[(size_t)n * HD2 + lane]);
        cs[nl * HD + lane * 2 + 0] = 0.9f * dv * sum.x + 0.1f * hv.x;
        cs[nl * HD + lane * 2 + 1] = 0.9f * dv * sum.y + 0.1f * hv.y;
    }
    __syncthreads();

    // GEMM phase: h = relu((1-b)*comb + b*comb@W)
    int jb = tid & 31, ng = tid >> 5;
    int j0 = jb * 4;
    float acc[4][4];
#pragma unroll
    for (int n = 0; n < 4; n++)
#pragma unroll
        for (int jj = 0; jj < 4; jj++) acc[n][jj] = 0.f;

    for (int kk = 0; kk < HD / 4; kk++) {
        float w[4][4];
#pragma unroll
        for (int q = 0; q < 4; q++) {
            float4 wv = *(const float4*)&W[(kk * 4 + q) * HD + j0];
            w[q][0] = wv.x; w[q][1] = wv.y; w[q][2] = wv.z; w[q][3] = wv.w;
        }
#pragma unroll
        for (int n = 0; n < 4; n++) {
            float4 c = *(const float4*)&cs[(ng * 4 + n) * HD + kk * 4];
#pragma unroll
            for (int jj = 0; jj < 4; jj++)
                acc[n][jj] = fmaf(c.x, w[0][jj],
                            fmaf(c.y, w[1][jj],
                            fmaf(c.z, w[2][jj],
                            fmaf(c.w, w[3][jj], acc[n][jj]))));
        }
    }

    float omb = 1.f - beta;
#pragma unroll
    for (int n = 0; n < 4; n++) {
        int gn = nb + ng * 4 + n;
        float4 cb = *(const float4*)&cs[(ng * 4 + n) * HD + j0];
        float* cp = (float*)&cb;
        float v[4];
#pragma unroll
        for (int jj = 0; jj < 4; jj++)
            v[jj] = fmaxf(omb * cp[jj] + beta * acc[n][jj], 0.f);
        if (OUT_MODE == 0) {
            float dv = dinv[gn];
            size_t base = (size_t)gn * HD2 + (j0 >> 1);
            gOut[base]     = __float22half2_rn(make_float2(dv * v[0], dv * v[1]));
            gOut[base + 1] = __float22half2_rn(make_float2(dv * v[2], dv * v[3]));
        } else {
            float4 ov = make_float4(v[0], v[1], v[2], v[3]);
            *(float4*)&hOut[(size_t)gn * HD + j0] = ov;
        }
    }
}

// ---------------- final: out = h@W2+b2; vis = relu(out@Wv+bv); txt = relu(out@Wt+bt) ----
// h (f32) lives in the same region as `out`: each block reads its own rows
// before writing them (intra-block sync), so no cross-block hazard.

__global__ __launch_bounds__(256) void k_final(const float* __restrict__ hIn,
                                               const float* __restrict__ W2,
                                               const float* __restrict__ b2,
                                               const float* __restrict__ Wv,
                                               const float* __restrict__ bv,
                                               const float* __restrict__ Wt,
                                               const float* __restrict__ bt,
                                               float* __restrict__ out,
                                               float* __restrict__ vis,
                                               float* __restrict__ txt) {
    __shared__ float hs[NPB * HD];
    __shared__ float os[NPB * HD];
    int tid = threadIdx.x;
    int nb = blockIdx.x * NPB;

    for (int idx = tid * 4; idx < NPB * HD; idx += 256 * 4)
        *(float4*)&hs[idx] = *(const float4*)&hIn[(size_t)nb * HD + idx];
    __syncthreads();

    int jb = tid & 31, ng = tid >> 5;
    int j0 = jb * 4;

    // out = h@W2 + b2 (no relu)
    {
        float acc[4][4];
#pragma unroll
        for (int n = 0; n < 4; n++)
#pragma unroll
            for (int jj = 0; jj < 4; jj++) acc[n][jj] = 0.f;
        for (int kk = 0; kk < HD / 4; kk++) {
            float w[4][4];
#pragma unroll
            for (int q = 0; q < 4; q++) {
                float4 wv = *(const float4*)&W2[(kk * 4 + q) * HD + j0];
                w[q][0] = wv.x; w[q][1] = wv.y; w[q][2] = wv.z; w[q][3] = wv.w;
            }
#pragma unroll
            for (int n = 0; n < 4; n++) {
                float4 c = *(const float4*)&hs[(ng * 4 + n) * HD + kk * 4];
#pragma unroll
                for (int jj = 0; jj < 4; jj++)
                    acc[n][jj] = fmaf(c.x, w[0][jj],
                                fmaf(c.y, w[1][jj],
                                fmaf(c.z, w[2][jj],
                                fmaf(c.w, w[3][jj], acc[n][jj]))));
            }
        }
#pragma unroll
        for (int n = 0; n < 4; n++) {
            int gn = nb + ng * 4 + n;
            float4 ov; float* op = (float*)&ov;
#pragma unroll
            for (int jj = 0; jj < 4; jj++) op[jj] = acc[n][jj] + b2[j0 + jj];
            *(float4*)&out[(size_t)gn * HD + j0] = ov;
            *(float4*)&os[(ng * 4 + n) * HD + j0] = ov;
        }
    }
    __syncthreads();

    const float* Ws[2] = {Wv, Wt};
    const float* bs[2] = {bv, bt};
    float* outs[2] = {vis, txt};
#pragma unroll
    for (int m = 0; m < 2; m++) {
        const float* Wm = Ws[m];
        const float* bm = bs[m];
        float* om = outs[m];
        float acc[4][4];
#pragma unroll
        for (int n = 0; n < 4; n++)
#pragma unroll
            for (int jj = 0; jj < 4; jj++) acc[n][jj] = 0.f;
        for (int kk = 0; kk < HD / 4; kk++) {
            float w[4][4];
#pragma unroll
            for (int q = 0; q < 4; q++) {
                float4 wv = *(const float4*)&Wm[(kk * 4 + q) * HD + j0];
                w[q][0] = wv.x; w[q][1] = wv.y; w[q][2] = wv.z; w[q][3] = wv.w;
            }
#pragma unroll
            for (int n = 0; n < 4; n++) {
                float4 c = *(const float4*)&os[(ng * 4 + n) * HD + kk * 4];
#pragma unroll
                for (int jj = 0; jj < 4; jj++)
                    acc[n][jj] = fmaf(c.x, w[0][jj],
                                fmaf(c.y, w[1][jj],
                                fmaf(c.z, w[2][jj],
                                fmaf(c.w, w[3][jj], acc[n][jj]))));
            }
        }
#pragma unroll
        for (int n = 0; n < 4; n++) {
            int gn = nb + ng * 4 + n;
            float4 ov; float* op = (float*)&ov;
#pragma unroll
            for (int jj = 0; jj < 4; jj++)
                op[jj] = fmaxf(acc[n][jj] + bm[j0 + jj], 0.f);
            *(float4*)&om[(size_t)gn * HD + j0] = ov;
        }
    }
}

// ---------------- launch ----------------

extern "C" void kernel_launch(void* const* d_in, const int* in_sizes, int n_in,
                              void* d_out, int out_size, void* d_ws, size_t ws_size,
                              hipStream_t stream) {
    (void)in_sizes; (void)n_in; (void)out_size; (void)ws_size;

    const float* x    = (const float*)d_in[0];
    const int*   edge = (const int*)d_in[1];   // [2,E]: src then dst
    const float* W1   = (const float*)d_in[2];
    const float* b1   = (const float*)d_in[3];
    const float* cw   = (const float*)d_in[4]; // [8,128,128]
    const float* W2   = (const float*)d_in[5];
    const float* b2   = (const float*)d_in[6];
    const float* Wv   = (const float*)d_in[7];
    const float* bv   = (const float*)d_in[8];
    const float* Wt   = (const float*)d_in[9];
    const float* bt   = (const float*)d_in[10];

    const int* esrc = edge;
    const int* edst = edge + NE;

    // d_out regions: [0]=h(f32, layer7 out) then `out`; [1]=h0(f16) then vis;
    // [2]=g ping-pong (2 x f16) then txt
    float* out0 = (float*)d_out;
    float* reg1 = out0 + (size_t)NN * HD;
    float* reg2 = reg1 + (size_t)NN * HD;

    __half2* h0h = (__half2*)reg1;
    __half2* ga  = (__half2*)reg2;
    __half2* gb  = (__half2*)((char*)reg2 + H16_BYTES);

    // workspace layout
    char* ws = (char*)d_ws;
    int*   deg_i = (int*)(ws + 0);          // N ints
    int*   fill  = (int*)(ws + 400000);     // N ints
    int*   rowp  = (int*)(ws + 800000);     // N+1 ints
    int*   bsums = (int*)(ws + 1200128);    // 128 ints
    int*   col   = (int*)(ws + 1200640);    // E ints
    float* dinv  = (float*)(ws + 5200640);  // N floats

    hipMemsetAsync(ws, 0, 800000, stream);  // deg_i + fill

    k_deg<<<(NE + 255) / 256, 256, 0, stream>>>(edst, deg_i);
    k_dinv<<<(NN + 255) / 256, 256, 0, stream>>>(deg_i, dinv);
    k_scan1<<<NBLK_SCAN, 1024, 0, stream>>>(deg_i, rowp, bsums);
    k_scan2<<<1, 128, 0, stream>>>(bsums);
    k_scan3<<<NBLK_SCAN, 1024, 0, stream>>>(rowp, bsums);
    k_fill<<<(NE + 255) / 256, 256, 0, stream>>>(esrc, edst, rowp, fill, col);

    k_init<<<NN / NPB, 256, 0, stream>>>(x, W1, b1, dinv, h0h, ga);

    // layers 0..6: f16 ping-pong (l even: ga->gb, odd: gb->ga). After l=6, g in gb.
    for (int l = 0; l < 7; l++) {
        float beta = (float)log(0.5 / (double)(l + 1) + 1.0);
        const __half2* gi = (l & 1) ? gb : ga;
        __half2*       go = (l & 1) ? ga : gb;
        k_layer<0><<<NN / NPB, 256, 0, stream>>>(gi, go, (float*)nullptr, h0h,
                                                 dinv, rowp, col,
                                                 cw + (size_t)l * HD * HD, beta);
    }
    // layer 7: gb -> f32 h in region0
    {
        float beta = (float)log(0.5 / 8.0 + 1.0);
        k_layer<1><<<NN / NPB, 256, 0, stream>>>(gb, (__half2*)nullptr, out0, h0h,
                                                 dinv, rowp, col,
                                                 cw + (size_t)7 * HD * HD, beta);
    }

    k_final<<<NN / NPB, 256, 0, stream>>>(out0, W2, b2, Wv, bv, Wt, bt,
                                          out0, reg1, reg2);
}

// Round 3
// 1101.166 us; speedup vs baseline: 1.6331x; 1.1504x over previous
//
#include <hip/hip_runtime.h>
#include <hip/hip_fp16.h>
#include <math.h>

#define NN 100000
#define NE 1000000
#define IND 256
#define HD  128
#define HD2 64           // half2 elements per row
#define NPB 32           // nodes per block in layer kernel
#define FNPB 64          // nodes per block in final kernel
#define NBLK_SCAN 98     // ceil(NN/1024)
#define H16_BYTES ((size_t)NN * HD * 2)   // 25,600,000

typedef _Float16 f16x8 __attribute__((ext_vector_type(8)));
typedef float f32x4 __attribute__((ext_vector_type(4)));

union U16 { uint4 u; __half2 h2[4]; __half h[8]; f16x8 v; };

// ---------------- CSR build ----------------

__global__ __launch_bounds__(256) void k_deg(const int* __restrict__ dst,
                                             int* __restrict__ deg) {
    int e = blockIdx.x * 256 + threadIdx.x;
    if (e < NE) atomicAdd(&deg[dst[e]], 1);
}

__global__ __launch_bounds__(256) void k_dinv(const int* __restrict__ deg,
                                              float* __restrict__ dinv) {
    int i = blockIdx.x * 256 + threadIdx.x;
    if (i < NN) dinv[i] = rsqrtf((float)(deg[i] + 1));  // +1 self-loop
}

__global__ __launch_bounds__(1024) void k_scan1(const int* __restrict__ deg,
                                                int* __restrict__ rowp,
                                                int* __restrict__ bsums) {
    __shared__ int s[1024];
    int t = threadIdx.x;
    int i = blockIdx.x * 1024 + t;
    int v = (i < NN) ? deg[i] : 0;
    s[t] = v;
    __syncthreads();
    for (int off = 1; off < 1024; off <<= 1) {
        int u = (t >= off) ? s[t - off] : 0;
        __syncthreads();
        s[t] += u;
        __syncthreads();
    }
    if (i < NN) rowp[i] = s[t] - v;
    if (t == 1023) bsums[blockIdx.x] = s[1023];
}

__global__ __launch_bounds__(128) void k_scan2(int* __restrict__ bsums) {
    __shared__ int s[128];
    int t = threadIdx.x;
    int v = (t < NBLK_SCAN) ? bsums[t] : 0;
    s[t] = v;
    __syncthreads();
    for (int off = 1; off < 128; off <<= 1) {
        int u = (t >= off) ? s[t - off] : 0;
        __syncthreads();
        s[t] += u;
        __syncthreads();
    }
    if (t < NBLK_SCAN) bsums[t] = s[t] - v;
}

__global__ __launch_bounds__(1024) void k_scan3(int* __restrict__ rowp,
                                                const int* __restrict__ bsums) {
    int i = blockIdx.x * 1024 + threadIdx.x;
    if (i < NN) rowp[i] += bsums[i >> 10];
    if (i == 0) rowp[NN] = NE;
}

__global__ __launch_bounds__(256) void k_fill(const int* __restrict__ src,
                                              const int* __restrict__ dst,
                                              const int* __restrict__ rowp,
                                              int* __restrict__ fill,
                                              int* __restrict__ col) {
    int e = blockIdx.x * 256 + threadIdx.x;
    if (e < NE) {
        int d = dst[e];
        int pos = rowp[d] + atomicAdd(&fill[d], 1);
        col[pos] = src[e];
    }
}

// ---------------- weight fragment pre-pack (11 matrices -> f16, B-frag order) ----
// frag layout: wf[m][((nt*4+ks)*64 + lane)*8 + j] = f16(W[ks*32+(lane>>4)*8+j][nt*16+(lane&15)])

__global__ __launch_bounds__(256) void k_wfrag(const float* __restrict__ cw,
                                               const float* __restrict__ W2,
                                               const float* __restrict__ Wv,
                                               const float* __restrict__ Wt,
                                               __half* __restrict__ wf) {
    int m = blockIdx.x >> 4;     // matrix 0..10
    int blk = blockIdx.x & 15;
    const float* W = (m < 8) ? (cw + (size_t)m * HD * HD)
                             : (m == 8 ? W2 : (m == 9 ? Wv : Wt));
    int i = (blk * 256 + threadIdx.x) * 4;   // element index k*128+col
    float4 v = *(const float4*)&W[i];
    int k = i >> 7, col0 = i & 127;
    float vv[4] = {v.x, v.y, v.z, v.w};
    __half* dstm = wf + (size_t)m * HD * HD;
    int ks = k >> 5, laneK = ((k >> 3) & 3) * 16, j = k & 7;
#pragma unroll
    for (int t = 0; t < 4; t++) {
        int col = col0 + t;
        int nt = col >> 4;
        int lane = laneK + (col & 15);
        dstm[((nt * 4 + ks) * 64 + lane) * 8 + j] = __float2half(vv[t]);
    }
}

// ---------------- initial transform: h0 = relu(x@W1+b1) (f16), g0 = dinv*h0 (f16) ----

__global__ __launch_bounds__(256) void k_init(const float* __restrict__ x,
                                              const float* __restrict__ W1,
                                              const float* __restrict__ b1,
                                              const float* __restrict__ dinv,
                                              __half2* __restrict__ h0h,
                                              __half2* __restrict__ g0) {
    __shared__ float xs[NPB * IND];  // 32 KB
    int tid = threadIdx.x;
    int nb = blockIdx.x * NPB;

    const float* xg = x + (size_t)nb * IND;
    for (int idx = tid * 4; idx < NPB * IND; idx += 256 * 4)
        *(float4*)&xs[idx] = *(const float4*)&xg[idx];
    __syncthreads();

    int jb = tid & 31, ng = tid >> 5;
    int j0 = jb * 4;
    float acc[4][4];
#pragma unroll
    for (int n = 0; n < 4; n++)
#pragma unroll
        for (int jj = 0; jj < 4; jj++) acc[n][jj] = 0.f;

    for (int kk = 0; kk < IND / 4; kk++) {
        float w[4][4];
#pragma unroll
        for (int q = 0; q < 4; q++) {
            float4 wv = *(const float4*)&W1[(kk * 4 + q) * HD + j0];
            w[q][0] = wv.x; w[q][1] = wv.y; w[q][2] = wv.z; w[q][3] = wv.w;
        }
#pragma unroll
        for (int n = 0; n < 4; n++) {
            float4 c = *(const float4*)&xs[(ng * 4 + n) * IND + kk * 4];
#pragma unroll
            for (int jj = 0; jj < 4; jj++)
                acc[n][jj] = fmaf(c.x, w[0][jj],
                            fmaf(c.y, w[1][jj],
                            fmaf(c.z, w[2][jj],
                            fmaf(c.w, w[3][jj], acc[n][jj]))));
        }
    }

#pragma unroll
    for (int n = 0; n < 4; n++) {
        int gn = nb + ng * 4 + n;
        float dv = dinv[gn];
        float v0 = fmaxf(acc[n][0] + b1[j0 + 0], 0.f);
        float v1 = fmaxf(acc[n][1] + b1[j0 + 1], 0.f);
        float v2 = fmaxf(acc[n][2] + b1[j0 + 2], 0.f);
        float v3 = fmaxf(acc[n][3] + b1[j0 + 3], 0.f);
        size_t base = (size_t)gn * HD2 + (j0 >> 1);
        h0h[base]     = __float22half2_rn(make_float2(v0, v1));
        h0h[base + 1] = __float22half2_rn(make_float2(v2, v3));
        g0[base]      = __float22half2_rn(make_float2(dv * v0, dv * v1));
        g0[base + 1]  = __float22half2_rn(make_float2(dv * v2, dv * v3));
    }
}

// ---------------- GCNII layer ----------------
// gather: 16 lanes x 16B cover a 256B row; 4 lane-groups process 4 edges/step.
// OUT_MODE 0: gOut = f16(dinv*h)   OUT_MODE 1: hOut = f32 h (last layer)

template <int OUT_MODE>
__global__ __launch_bounds__(256) void k_layer(const __half2* __restrict__ gIn,
                                               __half2* __restrict__ gOut,
                                               float* __restrict__ hOut,
                                               const __half2* __restrict__ h0,
                                               const float* __restrict__ dinv,
                                               const int* __restrict__ rowp,
                                               const int* __restrict__ col,
                                               const float* __restrict__ W,
                                               float beta) {
    __shared__ float cs[NPB * HD];  // 16 KB: comb rows (f32)
    int tid = threadIdx.x;
    int nb = blockIdx.x * NPB;
    int wave = tid >> 6, lane = tid & 63;
    int sub = lane & 15, grp = lane >> 4;
    const uint4* g4 = (const uint4*)gIn;   // 16 chunks of 16B per row

    for (int nl = wave; nl < NPB; nl += 4) {
        int n = nb + nl;
        float acc[8] = {0.f, 0.f, 0.f, 0.f, 0.f, 0.f, 0.f, 0.f};

        if (grp == 0) {   // self-loop contribution
            U16 v; v.u = g4[(size_t)n * 16 + sub];
#pragma unroll
            for (int q = 0; q < 4; q++) {
                float2 f = __half22float2(v.h2[q]);
                acc[q * 2] += f.x; acc[q * 2 + 1] += f.y;
            }
        }

        int end = rowp[n + 1];
        int e = rowp[n] + grp;
        for (; e + 4 < end; e += 8) {
            U16 va, vb;
            va.u = g4[(size_t)col[e] * 16 + sub];
            vb.u = g4[(size_t)col[e + 4] * 16 + sub];
#pragma unroll
            for (int q = 0; q < 4; q++) {
                float2 fa = __half22float2(va.h2[q]);
                float2 fb = __half22float2(vb.h2[q]);
                acc[q * 2] += fa.x + fb.x;
                acc[q * 2 + 1] += fa.y + fb.y;
            }
        }
        if (e < end) {
            U16 va; va.u = g4[(size_t)col[e] * 16 + sub];
#pragma unroll
            for (int q = 0; q < 4; q++) {
                float2 fa = __half22float2(va.h2[q]);
                acc[q * 2] += fa.x; acc[q * 2 + 1] += fa.y;
            }
        }

        // butterfly reduce across the 4 lane-groups
#pragma unroll
        for (int q = 0; q < 8; q++) {
            acc[q] += __shfl_xor(acc[q], 16);
            acc[q] += __shfl_xor(acc[q], 32);
        }

        // each lane writes 2 features: f = sub*8 + grp*2 + {0,1}
        float dv = dinv[n];
        float2 hf = __half22float2(h0[(size_t)n * HD2 + sub * 4 + grp]);
        float c0 = 0.9f * dv * acc[grp * 2]     + 0.1f * hf.x;
        float c1 = 0.9f * dv * acc[grp * 2 + 1] + 0.1f * hf.y;
        *(float2*)&cs[nl * HD + sub * 8 + grp * 2] = make_float2(c0, c1);
    }
    __syncthreads();

    // GEMM phase: h = relu((1-b)*comb + b*comb@W)
    int jb = tid & 31, ng = tid >> 5;
    int j0 = jb * 4;
    float acc[4][4];
#pragma unroll
    for (int n = 0; n < 4; n++)
#pragma unroll
        for (int jj = 0; jj < 4; jj++) acc[n][jj] = 0.f;

    for (int kk = 0; kk < HD / 4; kk++) {
        float w[4][4];
#pragma unroll
        for (int q = 0; q < 4; q++) {
            float4 wv = *(const float4*)&W[(kk * 4 + q) * HD + j0];
            w[q][0] = wv.x; w[q][1] = wv.y; w[q][2] = wv.z; w[q][3] = wv.w;
        }
#pragma unroll
        for (int n = 0; n < 4; n++) {
            float4 c = *(const float4*)&cs[(ng * 4 + n) * HD + kk * 4];
#pragma unroll
            for (int jj = 0; jj < 4; jj++)
                acc[n][jj] = fmaf(c.x, w[0][jj],
                            fmaf(c.y, w[1][jj],
                            fmaf(c.z, w[2][jj],
                            fmaf(c.w, w[3][jj], acc[n][jj]))));
        }
    }

    float omb = 1.f - beta;
#pragma unroll
    for (int n = 0; n < 4; n++) {
        int gn = nb + ng * 4 + n;
        float4 cb = *(const float4*)&cs[(ng * 4 + n) * HD + j0];
        float* cp = (float*)&cb;
        float v[4];
#pragma unroll
        for (int jj = 0; jj < 4; jj++)
            v[jj] = fmaxf(omb * cp[jj] + beta * acc[n][jj], 0.f);
        if (OUT_MODE == 0) {
            float dv = dinv[gn];
            size_t base = (size_t)gn * HD2 + (j0 >> 1);
            gOut[base]     = __float22half2_rn(make_float2(dv * v[0], dv * v[1]));
            gOut[base + 1] = __float22half2_rn(make_float2(dv * v[2], dv * v[3]));
        } else {
            *(float4*)&hOut[(size_t)gn * HD + j0] = make_float4(v[0], v[1], v[2], v[3]);
        }
    }
}

// ---------------- final (MFMA): out = h@W2+b2; vis = relu(out@Wv+bv); txt = relu(out@Wt+bt)

__global__ __launch_bounds__(256) void k_final(const float* __restrict__ hIn,
                                               const __half* __restrict__ wf,
                                               const float* __restrict__ b2,
                                               const float* __restrict__ bv,
                                               const float* __restrict__ bt,
                                               float* __restrict__ out,
                                               float* __restrict__ vis,
                                               float* __restrict__ txt) {
    __shared__ __half hs[FNPB * HD];  // 16 KB, XOR-swizzled rows
    __shared__ __half os[FNPB * HD];  // 16 KB, XOR-swizzled rows
    int tid = threadIdx.x;
    int nb = blockIdx.x * FNPB;
    int wave = tid >> 6, lane = tid & 63;

    // stage h rows as swizzled f16
#pragma unroll
    for (int it = 0; it < 4; it++) {
        int idx8 = it * 256 + tid;            // chunk of 8 floats; 64 rows x 16 chunks
        int row = idx8 >> 4, c8 = idx8 & 15;
        int gn = nb + row;
        float4 a = make_float4(0.f, 0.f, 0.f, 0.f), b = a;
        if (gn < NN) {
            a = *(const float4*)&hIn[(size_t)gn * HD + c8 * 8];
            b = *(const float4*)&hIn[(size_t)gn * HD + c8 * 8 + 4];
        }
        U16 p;
        p.h[0] = __float2half(a.x); p.h[1] = __float2half(a.y);
        p.h[2] = __float2half(a.z); p.h[3] = __float2half(a.w);
        p.h[4] = __float2half(b.x); p.h[5] = __float2half(b.y);
        p.h[6] = __float2half(b.z); p.h[7] = __float2half(b.w);
        int byte = (row * 256 + c8 * 16) ^ ((row & 7) << 4);
        *(uint4*)((char*)hs + byte) = p.u;
    }
    __syncthreads();

    const uint4* bf2 = (const uint4*)(wf + (size_t)8 * HD * HD);
    const uint4* bfv = (const uint4*)(wf + (size_t)9 * HD * HD);
    const uint4* bft = (const uint4*)(wf + (size_t)10 * HD * HD);

    int arow = wave * 16 + (lane & 15);
    int kb = (lane >> 4) * 8;

    // A-frags from hs
    f16x8 a[4];
#pragma unroll
    for (int ks = 0; ks < 4; ks++) {
        int byte = (arow * 256 + (ks * 32 + kb) * 2) ^ ((arow & 7) << 4);
        U16 r; r.u = *(const uint4*)((const char*)hs + byte);
        a[ks] = r.v;
    }

    // GEMM1: out = h@W2 + b2 ; also write f16 copy into os
#pragma unroll
    for (int nt = 0; nt < 8; nt++) {
        f32x4 acc = {0.f, 0.f, 0.f, 0.f};
#pragma unroll
        for (int ks = 0; ks < 4; ks++) {
            U16 bw; bw.u = bf2[(nt * 4 + ks) * 64 + lane];
            acc = __builtin_amdgcn_mfma_f32_16x16x32_f16(a[ks], bw.v, acc, 0, 0, 0);
        }
        int c = nt * 16 + (lane & 15);
        float bias = b2[c];
#pragma unroll
        for (int r = 0; r < 4; r++) {
            int lrow = wave * 16 + (lane >> 4) * 4 + r;
            float val = acc[r] + bias;
            int gn = nb + lrow;
            if (gn < NN) out[(size_t)gn * HD + c] = val;
            int byte = (lrow * 256 + c * 2) ^ ((lrow & 7) << 4);
            *(__half*)((char*)os + byte) = __float2half(val);
        }
    }
    __syncthreads();

    // A-frags from os
    f16x8 ao[4];
#pragma unroll
    for (int ks = 0; ks < 4; ks++) {
        int byte = (arow * 256 + (ks * 32 + kb) * 2) ^ ((arow & 7) << 4);
        U16 r; r.u = *(const uint4*)((const char*)os + byte);
        ao[ks] = r.v;
    }

    // GEMM2: vis = relu(out@Wv+bv); GEMM3: txt = relu(out@Wt+bt)
#pragma unroll
    for (int nt = 0; nt < 8; nt++) {
        f32x4 accv = {0.f, 0.f, 0.f, 0.f};
        f32x4 acct = {0.f, 0.f, 0.f, 0.f};
#pragma unroll
        for (int ks = 0; ks < 4; ks++) {
            U16 bwv; bwv.u = bfv[(nt * 4 + ks) * 64 + lane];
            U16 bwt; bwt.u = bft[(nt * 4 + ks) * 64 + lane];
            accv = __builtin_amdgcn_mfma_f32_16x16x32_f16(ao[ks], bwv.v, accv, 0, 0, 0);
            acct = __builtin_amdgcn_mfma_f32_16x16x32_f16(ao[ks], bwt.v, acct, 0, 0, 0);
        }
        int c = nt * 16 + (lane & 15);
        float biasv = bv[c], biast = bt[c];
#pragma unroll
        for (int r = 0; r < 4; r++) {
            int lrow = wave * 16 + (lane >> 4) * 4 + r;
            int gn = nb + lrow;
            if (gn < NN) {
                vis[(size_t)gn * HD + c] = fmaxf(accv[r] + biasv, 0.f);
                txt[(size_t)gn * HD + c] = fmaxf(acct[r] + biast, 0.f);
            }
        }
    }
}

// ---------------- launch ----------------

extern "C" void kernel_launch(void* const* d_in, const int* in_sizes, int n_in,
                              void* d_out, int out_size, void* d_ws, size_t ws_size,
                              hipStream_t stream) {
    (void)in_sizes; (void)n_in; (void)out_size; (void)ws_size;

    const float* x    = (const float*)d_in[0];
    const int*   edge = (const int*)d_in[1];   // [2,E]: src then dst
    const float* W1   = (const float*)d_in[2];
    const float* b1   = (const float*)d_in[3];
    const float* cw   = (const float*)d_in[4]; // [8,128,128]
    const float* W2   = (const float*)d_in[5];
    const float* b2   = (const float*)d_in[6];
    const float* Wv   = (const float*)d_in[7];
    const float* bv   = (const float*)d_in[8];
    const float* Wt   = (const float*)d_in[9];
    const float* bt   = (const float*)d_in[10];

    const int* esrc = edge;
    const int* edst = edge + NE;

    // d_out regions: [0]=h(f32, layer7 out) then `out`; [1]=h0(f16) then vis;
    // [2]=g ping-pong (2 x f16) then txt
    float* out0 = (float*)d_out;
    float* reg1 = out0 + (size_t)NN * HD;
    float* reg2 = reg1 + (size_t)NN * HD;

    __half2* h0h = (__half2*)reg1;
    __half2* ga  = (__half2*)reg2;
    __half2* gb  = (__half2*)((char*)reg2 + H16_BYTES);

    // workspace layout
    char* ws = (char*)d_ws;
    int*   deg_i = (int*)(ws + 0);          // N ints
    int*   fill  = (int*)(ws + 400000);     // N ints
    int*   rowp  = (int*)(ws + 800000);     // N+1 ints
    int*   bsums = (int*)(ws + 1200128);    // 128 ints
    int*   col   = (int*)(ws + 1200640);    // E ints
    float* dinv  = (float*)(ws + 5200640);  // N floats
    __half* wf   = (__half*)(ws + 5600640); // 11 * 128*128 halfs = 360448 B

    hipMemsetAsync(ws, 0, 800000, stream);  // deg_i + fill

    k_deg<<<(NE + 255) / 256, 256, 0, stream>>>(edst, deg_i);
    k_dinv<<<(NN + 255) / 256, 256, 0, stream>>>(deg_i, dinv);
    k_scan1<<<NBLK_SCAN, 1024, 0, stream>>>(deg_i, rowp, bsums);
    k_scan2<<<1, 128, 0, stream>>>(bsums);
    k_scan3<<<NBLK_SCAN, 1024, 0, stream>>>(rowp, bsums);
    k_fill<<<(NE + 255) / 256, 256, 0, stream>>>(esrc, edst, rowp, fill, col);
    k_wfrag<<<11 * 16, 256, 0, stream>>>(cw, W2, Wv, Wt, wf);

    k_init<<<NN / NPB, 256, 0, stream>>>(x, W1, b1, dinv, h0h, ga);

    // layers 0..6: f16 ping-pong (l even: ga->gb, odd: gb->ga). After l=6, g in gb.
    for (int l = 0; l < 7; l++) {
        float beta = (float)log(0.5 / (double)(l + 1) + 1.0);
        const __half2* gi = (l & 1) ? gb : ga;
        __half2*       go = (l & 1) ? ga : gb;
        k_layer<0><<<NN / NPB, 256, 0, stream>>>(gi, go, (float*)nullptr, h0h,
                                                 dinv, rowp, col,
                                                 cw + (size_t)l * HD * HD, beta);
    }
    // layer 7: gb -> f32 h in region0
    {
        float beta = (float)log(0.5 / 8.0 + 1.0);
        k_layer<1><<<NN / NPB, 256, 0, stream>>>(gb, (__half2*)nullptr, out0, h0h,
                                                 dinv, rowp, col,
                                                 cw + (size_t)7 * HD * HD, beta);
    }

    k_final<<<(NN + FNPB - 1) / FNPB, 256, 0, stream>>>(out0, wf, b2, bv, bt,
                                                        out0, reg1, reg2);
}

// Round 4
// 811.541 us; speedup vs baseline: 2.2159x; 1.3569x over previous
//
#include <hip/hip_runtime.h>
#include <hip/hip_fp16.h>
#include <math.h>

#define NN 100000
#define NE 1000000
#define IND 256
#define HD  128
#define HD2 64           // half2 elements per row
#define NPB 32           // nodes per block in layer kernel
#define FNPB 64          // nodes per block in final kernel
#define INPB 64          // nodes per block in init kernel
#define NBLK_SCAN 98     // ceil(NN/1024)
#define H16_BYTES ((size_t)NN * HD * 2)   // 25,600,000

typedef _Float16 f16x8 __attribute__((ext_vector_type(8)));
typedef float f32x4 __attribute__((ext_vector_type(4)));

union U16 { uint4 u; __half2 h2[4]; __half h[8]; f16x8 v; };

// ---------------- CSR build ----------------

__global__ __launch_bounds__(256) void k_deg(const int* __restrict__ dst,
                                             int* __restrict__ deg) {
    int e = blockIdx.x * 256 + threadIdx.x;
    if (e < NE) atomicAdd(&deg[dst[e]], 1);
}

__global__ __launch_bounds__(256) void k_dinv(const int* __restrict__ deg,
                                              float* __restrict__ dinv) {
    int i = blockIdx.x * 256 + threadIdx.x;
    if (i < NN) dinv[i] = rsqrtf((float)(deg[i] + 1));  // +1 self-loop
}

__global__ __launch_bounds__(1024) void k_scan1(const int* __restrict__ deg,
                                                int* __restrict__ rowp,
                                                int* __restrict__ bsums) {
    __shared__ int s[1024];
    int t = threadIdx.x;
    int i = blockIdx.x * 1024 + t;
    int v = (i < NN) ? deg[i] : 0;
    s[t] = v;
    __syncthreads();
    for (int off = 1; off < 1024; off <<= 1) {
        int u = (t >= off) ? s[t - off] : 0;
        __syncthreads();
        s[t] += u;
        __syncthreads();
    }
    if (i < NN) rowp[i] = s[t] - v;
    if (t == 1023) bsums[blockIdx.x] = s[1023];
}

__global__ __launch_bounds__(128) void k_scan2(int* __restrict__ bsums) {
    __shared__ int s[128];
    int t = threadIdx.x;
    int v = (t < NBLK_SCAN) ? bsums[t] : 0;
    s[t] = v;
    __syncthreads();
    for (int off = 1; off < 128; off <<= 1) {
        int u = (t >= off) ? s[t - off] : 0;
        __syncthreads();
        s[t] += u;
        __syncthreads();
    }
    if (t < NBLK_SCAN) bsums[t] = s[t] - v;
}

__global__ __launch_bounds__(1024) void k_scan3(int* __restrict__ rowp,
                                                const int* __restrict__ bsums) {
    int i = blockIdx.x * 1024 + threadIdx.x;
    if (i < NN) rowp[i] += bsums[i >> 10];
    if (i == 0) rowp[NN] = NE;
}

__global__ __launch_bounds__(256) void k_fill(const int* __restrict__ src,
                                              const int* __restrict__ dst,
                                              const int* __restrict__ rowp,
                                              int* __restrict__ fill,
                                              int* __restrict__ col) {
    int e = blockIdx.x * 256 + threadIdx.x;
    if (e < NE) {
        int d = dst[e];
        int pos = rowp[d] + atomicAdd(&fill[d], 1);
        col[pos] = src[e];
    }
}

// ---------------- weight fragment pre-pack ----------------
// KS=4 layout: wf[m][((nt*4+ks)*64+lane)*8+j] = f16(W[ks*32+(lane>>4)*8+j][nt*16+(lane&15)])

__global__ __launch_bounds__(256) void k_wfrag(const float* __restrict__ cw,
                                               const float* __restrict__ W2,
                                               const float* __restrict__ Wv,
                                               const float* __restrict__ Wt,
                                               __half* __restrict__ wf) {
    int m = blockIdx.x >> 4;     // matrix 0..10
    int blk = blockIdx.x & 15;
    const float* W = (m < 8) ? (cw + (size_t)m * HD * HD)
                             : (m == 8 ? W2 : (m == 9 ? Wv : Wt));
    int i = (blk * 256 + threadIdx.x) * 4;   // element index k*128+col
    float4 v = *(const float4*)&W[i];
    int k = i >> 7, col0 = i & 127;
    float vv[4] = {v.x, v.y, v.z, v.w};
    __half* dstm = wf + (size_t)m * HD * HD;
    int ks = k >> 5, laneK = ((k >> 3) & 3) * 16, j = k & 7;
#pragma unroll
    for (int t = 0; t < 4; t++) {
        int col = col0 + t;
        int nt = col >> 4;
        int lane = laneK + (col & 15);
        dstm[((nt * 4 + ks) * 64 + lane) * 8 + j] = __float2half(vv[t]);
    }
}

// W1 [256,128], KS=8: w1f[((nt*8+ks)*64+lane)*8+j] = f16(W1[ks*32+(lane>>4)*8+j][nt*16+(lane&15)])

__global__ __launch_bounds__(256) void k_w1frag(const float* __restrict__ W1,
                                                __half* __restrict__ w1f) {
    int i = (blockIdx.x * 256 + threadIdx.x) * 4;   // k*128+col, total 32768
    float4 v = *(const float4*)&W1[i];
    int k = i >> 7, col0 = i & 127;
    float vv[4] = {v.x, v.y, v.z, v.w};
    int ks = k >> 5, laneK = ((k >> 3) & 3) * 16, j = k & 7;
#pragma unroll
    for (int t = 0; t < 4; t++) {
        int col = col0 + t;
        int nt = col >> 4;
        int lane = laneK + (col & 15);
        w1f[((nt * 8 + ks) * 64 + lane) * 8 + j] = __float2half(vv[t]);
    }
}

// ---------------- initial transform (MFMA): h0 = relu(x@W1+b1) f16, g0 = dinv*h0 f16 ----

__global__ __launch_bounds__(256) void k_init(const float* __restrict__ x,
                                              const __half* __restrict__ w1f,
                                              const float* __restrict__ b1,
                                              const float* __restrict__ dinv,
                                              __half* __restrict__ h0h,
                                              __half* __restrict__ g0) {
    __shared__ char lds[32768];     // xs (swizzled f16 64x256), later hb/gb
    int tid = threadIdx.x;
    int nb = blockIdx.x * INPB;
    int wv = tid >> 6, lane = tid & 63;

    // stage x -> f16 swizzled (rows of 512B)
#pragma unroll
    for (int it = 0; it < 8; it++) {
        int c = it * 256 + tid;          // chunk of 8 floats: 64 rows x 32 chunks
        int row = c >> 5, k8 = c & 31;
        int gn = nb + row;
        float4 a = make_float4(0.f, 0.f, 0.f, 0.f), b = a;
        if (gn < NN) {
            a = *(const float4*)&x[(size_t)gn * IND + k8 * 8];
            b = *(const float4*)&x[(size_t)gn * IND + k8 * 8 + 4];
        }
        U16 p;
        p.h[0] = __float2half(a.x); p.h[1] = __float2half(a.y);
        p.h[2] = __float2half(a.z); p.h[3] = __float2half(a.w);
        p.h[4] = __float2half(b.x); p.h[5] = __float2half(b.y);
        p.h[6] = __float2half(b.z); p.h[7] = __float2half(b.w);
        int byte = (row * 512 + k8 * 16) ^ ((row & 7) << 4);
        *(uint4*)(lds + byte) = p.u;
    }
    __syncthreads();

    // A-frags: wave = row-tile
    int arow = wv * 16 + (lane & 15);
    f16x8 a[8];
#pragma unroll
    for (int ks = 0; ks < 8; ks++) {
        int byte = (arow * 512 + ks * 64 + (lane >> 4) * 16) ^ ((arow & 7) << 4);
        U16 r; r.u = *(const uint4*)(lds + byte);
        a[ks] = r.v;
    }
    __syncthreads();   // all waves done reading xs before epilogue overwrites

    __half* hb = (__half*)lds;            // 64x128 f16 linear
    __half* gbuf = (__half*)(lds + 16384);
    const uint4* bf = (const uint4*)w1f;

#pragma unroll
    for (int nt = 0; nt < 8; nt++) {
        f32x4 acc = {0.f, 0.f, 0.f, 0.f};
#pragma unroll
        for (int ks = 0; ks < 8; ks++) {
            U16 bw; bw.u = bf[(nt * 8 + ks) * 64 + lane];
            acc = __builtin_amdgcn_mfma_f32_16x16x32_f16(a[ks], bw.v, acc, 0, 0, 0);
        }
        int colb = nt * 16 + (lane & 15);
        float bias = b1[colb];
#pragma unroll
        for (int r = 0; r < 4; r++) {
            int row = wv * 16 + (lane >> 4) * 4 + r;
            int gn = nb + row;
            float dv = (gn < NN) ? dinv[gn] : 0.f;
            float v = fmaxf(acc[r] + bias, 0.f);
            hb[row * HD + colb] = __float2half(v);
            gbuf[row * HD + colb] = __float2half(dv * v);
        }
    }
    __syncthreads();

    // coalesced copy-out
#pragma unroll
    for (int it = 0; it < 4; it++) {
        int c = it * 256 + tid;          // 1024 chunks of 16B per buffer
        int row = c >> 4;
        if (nb + row < NN) {
            *(uint4*)((char*)h0h + (size_t)nb * 256 + c * 16) = *(uint4*)((char*)hb + c * 16);
            *(uint4*)((char*)g0 + (size_t)nb * 256 + c * 16) = *(uint4*)((char*)gbuf + c * 16);
        }
    }
}

// ---------------- GCNII layer ----------------
// gather: 16 lanes x 16B cover a 256B row; 4 lane-groups process 4 edges/step.
// GEMM: MFMA on f16 comb (csh swizzled), exact f32 comb kept in cs for epilogue.
// OUT_MODE 0: gOut = f16(dinv*h)   OUT_MODE 1: hOut = f32 h (last layer)

template <int OUT_MODE>
__global__ __launch_bounds__(256) void k_layer(const __half2* __restrict__ gIn,
                                               __half* __restrict__ gOutH,
                                               float* __restrict__ hOut,
                                               const __half2* __restrict__ h0,
                                               const float* __restrict__ dinv,
                                               const int* __restrict__ rowp,
                                               const int* __restrict__ col,
                                               const __half* __restrict__ wfL,
                                               float beta) {
    __shared__ float cs[NPB * HD];      // 16 KB: comb rows (f32, linear)
    __shared__ __half csh[NPB * HD];    // 8 KB: comb f16, swizzled; reused for output
    int tid = threadIdx.x;
    int nb = blockIdx.x * NPB;
    int wave = tid >> 6, lane = tid & 63;
    int sub = lane & 15, grp = lane >> 4;
    const uint4* g4 = (const uint4*)gIn;   // 16 chunks of 16B per row

    for (int nl = wave; nl < NPB; nl += 4) {
        int n = nb + nl;
        float acc[8] = {0.f, 0.f, 0.f, 0.f, 0.f, 0.f, 0.f, 0.f};

        if (grp == 0) {   // self-loop contribution
            U16 v; v.u = g4[(size_t)n * 16 + sub];
#pragma unroll
            for (int q = 0; q < 4; q++) {
                float2 f = __half22float2(v.h2[q]);
                acc[q * 2] += f.x; acc[q * 2 + 1] += f.y;
            }
        }

        int end = rowp[n + 1];
        int e = rowp[n] + grp;
        for (; e + 4 < end; e += 8) {
            U16 va, vb;
            va.u = g4[(size_t)col[e] * 16 + sub];
            vb.u = g4[(size_t)col[e + 4] * 16 + sub];
#pragma unroll
            for (int q = 0; q < 4; q++) {
                float2 fa = __half22float2(va.h2[q]);
                float2 fb = __half22float2(vb.h2[q]);
                acc[q * 2] += fa.x + fb.x;
                acc[q * 2 + 1] += fa.y + fb.y;
            }
        }
        if (e < end) {
            U16 va; va.u = g4[(size_t)col[e] * 16 + sub];
#pragma unroll
            for (int q = 0; q < 4; q++) {
                float2 fa = __half22float2(va.h2[q]);
                acc[q * 2] += fa.x; acc[q * 2 + 1] += fa.y;
            }
        }

        // butterfly reduce across the 4 lane-groups
#pragma unroll
        for (int q = 0; q < 8; q++) {
            acc[q] += __shfl_xor(acc[q], 16);
            acc[q] += __shfl_xor(acc[q], 32);
        }

        // each lane writes 2 features: f = sub*8 + grp*2 + {0,1}
        float dv = dinv[n];
        float2 hf = __half22float2(h0[(size_t)n * HD2 + sub * 4 + grp]);
        float c0 = 0.9f * dv * acc[grp * 2]     + 0.1f * hf.x;
        float c1 = 0.9f * dv * acc[grp * 2 + 1] + 0.1f * hf.y;
        *(float2*)&cs[nl * HD + sub * 8 + grp * 2] = make_float2(c0, c1);
        int fbyte = (nl * 256 + (sub * 8 + grp * 2) * 2) ^ ((nl & 7) << 4);
        *(__half2*)((char*)csh + fbyte) = __float22half2_rn(make_float2(c0, c1));
    }
    __syncthreads();

    // MFMA GEMM: 2 row-tiles x 8 col-tiles, 4 tiles/wave
    int rt = wave >> 1;
    int ntb = (wave & 1) * 4;
    int arow = rt * 16 + (lane & 15);
    f16x8 a[4];
#pragma unroll
    for (int ks = 0; ks < 4; ks++) {
        int byte = (arow * 256 + ks * 64 + (lane >> 4) * 16) ^ ((arow & 7) << 4);
        U16 r; r.u = *(const uint4*)((const char*)csh + byte);
        a[ks] = r.v;
    }
    __syncthreads();   // a-frags in regs; csh reusable as output buffer

    const uint4* bf = (const uint4*)wfL;
    float omb = 1.f - beta;
#pragma unroll
    for (int nt2 = 0; nt2 < 4; nt2++) {
        int nt = ntb + nt2;
        f32x4 acc = {0.f, 0.f, 0.f, 0.f};
#pragma unroll
        for (int ks = 0; ks < 4; ks++) {
            U16 bw; bw.u = bf[(nt * 4 + ks) * 64 + lane];
            acc = __builtin_amdgcn_mfma_f32_16x16x32_f16(a[ks], bw.v, acc, 0, 0, 0);
        }
        int colb = nt * 16 + (lane & 15);
#pragma unroll
        for (int r = 0; r < 4; r++) {
            int row = rt * 16 + (lane >> 4) * 4 + r;
            int gn = nb + row;
            float comb = cs[row * HD + colb];
            float v = fmaxf(omb * comb + beta * acc[r], 0.f);
            if (OUT_MODE == 0) {
                csh[row * HD + colb] = __float2half(dinv[gn] * v);
            } else {
                hOut[(size_t)gn * HD + colb] = v;
            }
        }
    }
    if (OUT_MODE == 0) {
        __syncthreads();
        // coalesced copy-out: 32 rows x 256B = 512 chunks of 16B
#pragma unroll
        for (int it = 0; it < 2; it++) {
            int c = it * 256 + tid;
            *(uint4*)((char*)gOutH + (size_t)nb * 256 + c * 16) =
                *(uint4*)((char*)csh + c * 16);
        }
    }
}

// ---------------- final (MFMA): out = h@W2+b2; vis = relu(out@Wv+bv); txt = relu(out@Wt+bt)

__global__ __launch_bounds__(256) void k_final(const float* __restrict__ hIn,
                                               const __half* __restrict__ wf,
                                               const float* __restrict__ b2,
                                               const float* __restrict__ bv,
                                               const float* __restrict__ bt,
                                               float* __restrict__ out,
                                               float* __restrict__ vis,
                                               float* __restrict__ txt) {
    __shared__ __half hs[FNPB * HD];  // 16 KB, XOR-swizzled rows
    __shared__ __half os[FNPB * HD];  // 16 KB, XOR-swizzled rows
    int tid = threadIdx.x;
    int nb = blockIdx.x * FNPB;
    int wave = tid >> 6, lane = tid & 63;

    // stage h rows as swizzled f16
#pragma unroll
    for (int it = 0; it < 4; it++) {
        int idx8 = it * 256 + tid;            // chunk of 8 floats; 64 rows x 16 chunks
        int row = idx8 >> 4, c8 = idx8 & 15;
        int gn = nb + row;
        float4 a = make_float4(0.f, 0.f, 0.f, 0.f), b = a;
        if (gn < NN) {
            a = *(const float4*)&hIn[(size_t)gn * HD + c8 * 8];
            b = *(const float4*)&hIn[(size_t)gn * HD + c8 * 8 + 4];
        }
        U16 p;
        p.h[0] = __float2half(a.x); p.h[1] = __float2half(a.y);
        p.h[2] = __float2half(a.z); p.h[3] = __float2half(a.w);
        p.h[4] = __float2half(b.x); p.h[5] = __float2half(b.y);
        p.h[6] = __float2half(b.z); p.h[7] = __float2half(b.w);
        int byte = (row * 256 + c8 * 16) ^ ((row & 7) << 4);
        *(uint4*)((char*)hs + byte) = p.u;
    }
    __syncthreads();

    const uint4* bf2 = (const uint4*)(wf + (size_t)8 * HD * HD);
    const uint4* bfv = (const uint4*)(wf + (size_t)9 * HD * HD);
    const uint4* bft = (const uint4*)(wf + (size_t)10 * HD * HD);

    int arow = wave * 16 + (lane & 15);
    int kb = (lane >> 4) * 8;

    // A-frags from hs
    f16x8 a[4];
#pragma unroll
    for (int ks = 0; ks < 4; ks++) {
        int byte = (arow * 256 + (ks * 32 + kb) * 2) ^ ((arow & 7) << 4);
        U16 r; r.u = *(const uint4*)((const char*)hs + byte);
        a[ks] = r.v;
    }

    // GEMM1: out = h@W2 + b2 ; also write f16 copy into os
#pragma unroll
    for (int nt = 0; nt < 8; nt++) {
        f32x4 acc = {0.f, 0.f, 0.f, 0.f};
#pragma unroll
        for (int ks = 0; ks < 4; ks++) {
            U16 bw; bw.u = bf2[(nt * 4 + ks) * 64 + lane];
            acc = __builtin_amdgcn_mfma_f32_16x16x32_f16(a[ks], bw.v, acc, 0, 0, 0);
        }
        int c = nt * 16 + (lane & 15);
        float bias = b2[c];
#pragma unroll
        for (int r = 0; r < 4; r++) {
            int lrow = wave * 16 + (lane >> 4) * 4 + r;
            float val = acc[r] + bias;
            int gn = nb + lrow;
            if (gn < NN) out[(size_t)gn * HD + c] = val;
            int byte = (lrow * 256 + c * 2) ^ ((lrow & 7) << 4);
            *(__half*)((char*)os + byte) = __float2half(val);
        }
    }
    __syncthreads();

    // A-frags from os
    f16x8 ao[4];
#pragma unroll
    for (int ks = 0; ks < 4; ks++) {
        int byte = (arow * 256 + (ks * 32 + kb) * 2) ^ ((arow & 7) << 4);
        U16 r; r.u = *(const uint4*)((const char*)os + byte);
        ao[ks] = r.v;
    }

    // GEMM2: vis = relu(out@Wv+bv); GEMM3: txt = relu(out@Wt+bt)
#pragma unroll
    for (int nt = 0; nt < 8; nt++) {
        f32x4 accv = {0.f, 0.f, 0.f, 0.f};
        f32x4 acct = {0.f, 0.f, 0.f, 0.f};
#pragma unroll
        for (int ks = 0; ks < 4; ks++) {
            U16 bwv; bwv.u = bfv[(nt * 4 + ks) * 64 + lane];
            U16 bwt; bwt.u = bft[(nt * 4 + ks) * 64 + lane];
            accv = __builtin_amdgcn_mfma_f32_16x16x32_f16(ao[ks], bwv.v, accv, 0, 0, 0);
            acct = __builtin_amdgcn_mfma_f32_16x16x32_f16(ao[ks], bwt.v, acct, 0, 0, 0);
        }
        int c = nt * 16 + (lane & 15);
        float biasv = bv[c], biast = bt[c];
#pragma unroll
        for (int r = 0; r < 4; r++) {
            int lrow = wave * 16 + (lane >> 4) * 4 + r;
            int gn = nb + lrow;
            if (gn < NN) {
                vis[(size_t)gn * HD + c] = fmaxf(accv[r] + biasv, 0.f);
                txt[(size_t)gn * HD + c] = fmaxf(acct[r] + biast, 0.f);
            }
        }
    }
}

// ---------------- launch ----------------

extern "C" void kernel_launch(void* const* d_in, const int* in_sizes, int n_in,
                              void* d_out, int out_size, void* d_ws, size_t ws_size,
                              hipStream_t stream) {
    (void)in_sizes; (void)n_in; (void)out_size; (void)ws_size;

    const float* x    = (const float*)d_in[0];
    const int*   edge = (const int*)d_in[1];   // [2,E]: src then dst
    const float* W1   = (const float*)d_in[2];
    const float* b1   = (const float*)d_in[3];
    const float* cw   = (const float*)d_in[4]; // [8,128,128]
    const float* W2   = (const float*)d_in[5];
    const float* b2   = (const float*)d_in[6];
    const float* Wv   = (const float*)d_in[7];
    const float* bv   = (const float*)d_in[8];
    const float* Wt   = (const float*)d_in[9];
    const float* bt   = (const float*)d_in[10];

    const int* esrc = edge;
    const int* edst = edge + NE;

    // d_out regions: [0]=h(f32, layer7 out) then `out`; [1]=h0(f16) then vis;
    // [2]=g ping-pong (2 x f16) then txt
    float* out0 = (float*)d_out;
    float* reg1 = out0 + (size_t)NN * HD;
    float* reg2 = reg1 + (size_t)NN * HD;

    __half* h0h = (__half*)reg1;
    __half* ga  = (__half*)reg2;
    __half* gb  = (__half*)((char*)reg2 + H16_BYTES);

    // workspace layout
    char* ws = (char*)d_ws;
    int*   deg_i = (int*)(ws + 0);          // N ints
    int*   fill  = (int*)(ws + 400000);     // N ints
    int*   rowp  = (int*)(ws + 800000);     // N+1 ints
    int*   bsums = (int*)(ws + 1200128);    // 128 ints
    int*   col   = (int*)(ws + 1200640);    // E ints
    float* dinv  = (float*)(ws + 5200640);  // N floats
    __half* wf   = (__half*)(ws + 5600640); // 11 * 128*128 halfs = 360448 B
    __half* w1f  = (__half*)(ws + 5961088); // 256*128 halfs = 65536 B

    hipMemsetAsync(ws, 0, 800000, stream);  // deg_i + fill

    k_deg<<<(NE + 255) / 256, 256, 0, stream>>>(edst, deg_i);
    k_dinv<<<(NN + 255) / 256, 256, 0, stream>>>(deg_i, dinv);
    k_scan1<<<NBLK_SCAN, 1024, 0, stream>>>(deg_i, rowp, bsums);
    k_scan2<<<1, 128, 0, stream>>>(bsums);
    k_scan3<<<NBLK_SCAN, 1024, 0, stream>>>(rowp, bsums);
    k_fill<<<(NE + 255) / 256, 256, 0, stream>>>(esrc, edst, rowp, fill, col);
    k_wfrag<<<11 * 16, 256, 0, stream>>>(cw, W2, Wv, Wt, wf);
    k_w1frag<<<32, 256, 0, stream>>>(W1, w1f);

    k_init<<<(NN + INPB - 1) / INPB, 256, 0, stream>>>(x, w1f, b1, dinv, h0h, ga);

    // layers 0..6: f16 ping-pong (l even: ga->gb, odd: gb->ga). After l=6, g in gb.
    for (int l = 0; l < 7; l++) {
        float beta = (float)log(0.5 / (double)(l + 1) + 1.0);
        const __half* gi = (l & 1) ? gb : ga;
        __half*       go = (l & 1) ? ga : gb;
        k_layer<0><<<NN / NPB, 256, 0, stream>>>((const __half2*)gi, go,
                                                 (float*)nullptr, (const __half2*)h0h,
                                                 dinv, rowp, col,
                                                 wf + (size_t)l * HD * HD, beta);
    }
    // layer 7: gb -> f32 h in region0
    {
        float beta = (float)log(0.5 / 8.0 + 1.0);
        k_layer<1><<<NN / NPB, 256, 0, stream>>>((const __half2*)gb, (__half*)nullptr,
                                                 out0, (const __half2*)h0h,
                                                 dinv, rowp, col,
                                                 wf + (size_t)7 * HD * HD, beta);
    }

    k_final<<<(NN + FNPB - 1) / FNPB, 256, 0, stream>>>(out0, wf, b2, bv, bt,
                                                        out0, reg1, reg2);
}

// Round 5
// 639.622 us; speedup vs baseline: 2.8115x; 1.2688x over previous
//
#include <hip/hip_runtime.h>
#include <hip/hip_fp16.h>
#include <math.h>

#define NN 100000
#define NE 1000000
#define IND 256
#define HD  128
#define HD2 64           // half2 elements per row
#define NPB 32           // nodes per block in layer kernel
#define FNPB 64          // nodes per block in final kernel
#define INPB 64          // nodes per block in init kernel
#define NBLK_SCAN 98     // ceil(NN/1024)
#define ECAP 768         // staged edges per block (avg 320, Poisson tail-safe + guarded)
#define H16_BYTES ((size_t)NN * HD * 2)   // 25,600,000

typedef _Float16 f16x8 __attribute__((ext_vector_type(8)));
typedef float f32x4 __attribute__((ext_vector_type(4)));

union U16 { uint4 u; __half2 h2[4]; __half h[8]; f16x8 v; };

// ---------------- CSR build ----------------

__global__ __launch_bounds__(256) void k_deg(const int* __restrict__ dst,
                                             int* __restrict__ deg) {
    int e = blockIdx.x * 256 + threadIdx.x;
    if (e < NE) atomicAdd(&deg[dst[e]], 1);
}

__global__ __launch_bounds__(256) void k_dinv(const int* __restrict__ deg,
                                              float* __restrict__ dinv) {
    int i = blockIdx.x * 256 + threadIdx.x;
    if (i < NN) dinv[i] = rsqrtf((float)(deg[i] + 1));  // +1 self-loop
}

__global__ __launch_bounds__(1024) void k_scan1(const int* __restrict__ deg,
                                                int* __restrict__ rowp,
                                                int* __restrict__ bsums) {
    __shared__ int s[1024];
    int t = threadIdx.x;
    int i = blockIdx.x * 1024 + t;
    int v = (i < NN) ? deg[i] : 0;
    s[t] = v;
    __syncthreads();
    for (int off = 1; off < 1024; off <<= 1) {
        int u = (t >= off) ? s[t - off] : 0;
        __syncthreads();
        s[t] += u;
        __syncthreads();
    }
    if (i < NN) rowp[i] = s[t] - v;
    if (t == 1023) bsums[blockIdx.x] = s[1023];
}

__global__ __launch_bounds__(128) void k_scan2(int* __restrict__ bsums) {
    __shared__ int s[128];
    int t = threadIdx.x;
    int v = (t < NBLK_SCAN) ? bsums[t] : 0;
    s[t] = v;
    __syncthreads();
    for (int off = 1; off < 128; off <<= 1) {
        int u = (t >= off) ? s[t - off] : 0;
        __syncthreads();
        s[t] += u;
        __syncthreads();
    }
    if (t < NBLK_SCAN) bsums[t] = s[t] - v;
}

__global__ __launch_bounds__(1024) void k_scan3(int* __restrict__ rowp,
                                                const int* __restrict__ bsums) {
    int i = blockIdx.x * 1024 + threadIdx.x;
    if (i < NN) rowp[i] += bsums[i >> 10];
    if (i == 0) rowp[NN] = NE;
}

__global__ __launch_bounds__(256) void k_fill(const int* __restrict__ src,
                                              const int* __restrict__ dst,
                                              const int* __restrict__ rowp,
                                              int* __restrict__ fill,
                                              int* __restrict__ col) {
    int e = blockIdx.x * 256 + threadIdx.x;
    if (e < NE) {
        int d = dst[e];
        int pos = rowp[d] + atomicAdd(&fill[d], 1);
        col[pos] = src[e];
    }
}

// ---------------- weight fragment pre-pack ----------------
// KS=4 layout: wf[m][((nt*4+ks)*64+lane)*8+j] = f16(W[ks*32+(lane>>4)*8+j][nt*16+(lane&15)])

__global__ __launch_bounds__(256) void k_wfrag(const float* __restrict__ cw,
                                               const float* __restrict__ W2,
                                               const float* __restrict__ Wv,
                                               const float* __restrict__ Wt,
                                               __half* __restrict__ wf) {
    int m = blockIdx.x >> 4;     // matrix 0..10
    int blk = blockIdx.x & 15;
    const float* W = (m < 8) ? (cw + (size_t)m * HD * HD)
                             : (m == 8 ? W2 : (m == 9 ? Wv : Wt));
    int i = (blk * 256 + threadIdx.x) * 4;   // element index k*128+col
    float4 v = *(const float4*)&W[i];
    int k = i >> 7, col0 = i & 127;
    float vv[4] = {v.x, v.y, v.z, v.w};
    __half* dstm = wf + (size_t)m * HD * HD;
    int ks = k >> 5, laneK = ((k >> 3) & 3) * 16, j = k & 7;
#pragma unroll
    for (int t = 0; t < 4; t++) {
        int col = col0 + t;
        int nt = col >> 4;
        int lane = laneK + (col & 15);
        dstm[((nt * 4 + ks) * 64 + lane) * 8 + j] = __float2half(vv[t]);
    }
}

// W1 [256,128], KS=8: w1f[((nt*8+ks)*64+lane)*8+j] = f16(W1[ks*32+(lane>>4)*8+j][nt*16+(lane&15)])

__global__ __launch_bounds__(256) void k_w1frag(const float* __restrict__ W1,
                                                __half* __restrict__ w1f) {
    int i = (blockIdx.x * 256 + threadIdx.x) * 4;   // k*128+col, total 32768
    float4 v = *(const float4*)&W1[i];
    int k = i >> 7, col0 = i & 127;
    float vv[4] = {v.x, v.y, v.z, v.w};
    int ks = k >> 5, laneK = ((k >> 3) & 3) * 16, j = k & 7;
#pragma unroll
    for (int t = 0; t < 4; t++) {
        int col = col0 + t;
        int nt = col >> 4;
        int lane = laneK + (col & 15);
        w1f[((nt * 8 + ks) * 64 + lane) * 8 + j] = __float2half(vv[t]);
    }
}

// ---------------- initial transform (MFMA): h0 = relu(x@W1+b1) f16, g0 = dinv*h0 f16 ----

__global__ __launch_bounds__(256) void k_init(const float* __restrict__ x,
                                              const __half* __restrict__ w1f,
                                              const float* __restrict__ b1,
                                              const float* __restrict__ dinv,
                                              __half* __restrict__ h0h,
                                              __half* __restrict__ g0) {
    __shared__ char lds[32768];     // xs (swizzled f16 64x256), later hb/gb
    int tid = threadIdx.x;
    int nb = blockIdx.x * INPB;
    int wv = tid >> 6, lane = tid & 63;

    // stage x -> f16 swizzled (rows of 512B)
#pragma unroll
    for (int it = 0; it < 8; it++) {
        int c = it * 256 + tid;          // chunk of 8 floats: 64 rows x 32 chunks
        int row = c >> 5, k8 = c & 31;
        int gn = nb + row;
        float4 a = make_float4(0.f, 0.f, 0.f, 0.f), b = a;
        if (gn < NN) {
            a = *(const float4*)&x[(size_t)gn * IND + k8 * 8];
            b = *(const float4*)&x[(size_t)gn * IND + k8 * 8 + 4];
        }
        U16 p;
        p.h[0] = __float2half(a.x); p.h[1] = __float2half(a.y);
        p.h[2] = __float2half(a.z); p.h[3] = __float2half(a.w);
        p.h[4] = __float2half(b.x); p.h[5] = __float2half(b.y);
        p.h[6] = __float2half(b.z); p.h[7] = __float2half(b.w);
        int byte = (row * 512 + k8 * 16) ^ ((row & 7) << 4);
        *(uint4*)(lds + byte) = p.u;
    }
    __syncthreads();

    // A-frags: wave = row-tile
    int arow = wv * 16 + (lane & 15);
    f16x8 a[8];
#pragma unroll
    for (int ks = 0; ks < 8; ks++) {
        int byte = (arow * 512 + ks * 64 + (lane >> 4) * 16) ^ ((arow & 7) << 4);
        U16 r; r.u = *(const uint4*)(lds + byte);
        a[ks] = r.v;
    }
    __syncthreads();   // all waves done reading xs before epilogue overwrites

    __half* hb = (__half*)lds;            // 64x128 f16 linear
    __half* gbuf = (__half*)(lds + 16384);
    const uint4* bf = (const uint4*)w1f;

#pragma unroll
    for (int nt = 0; nt < 8; nt++) {
        f32x4 acc = {0.f, 0.f, 0.f, 0.f};
#pragma unroll
        for (int ks = 0; ks < 8; ks++) {
            U16 bw; bw.u = bf[(nt * 8 + ks) * 64 + lane];
            acc = __builtin_amdgcn_mfma_f32_16x16x32_f16(a[ks], bw.v, acc, 0, 0, 0);
        }
        int colb = nt * 16 + (lane & 15);
        float bias = b1[colb];
#pragma unroll
        for (int r = 0; r < 4; r++) {
            int row = wv * 16 + (lane >> 4) * 4 + r;
            int gn = nb + row;
            float dv = (gn < NN) ? dinv[gn] : 0.f;
            float v = fmaxf(acc[r] + bias, 0.f);
            hb[row * HD + colb] = __float2half(v);
            gbuf[row * HD + colb] = __float2half(dv * v);
        }
    }
    __syncthreads();

    // coalesced copy-out
#pragma unroll
    for (int it = 0; it < 4; it++) {
        int c = it * 256 + tid;          // 1024 chunks of 16B per buffer
        int row = c >> 4;
        if (nb + row < NN) {
            *(uint4*)((char*)h0h + (size_t)nb * 256 + c * 16) = *(uint4*)((char*)hb + c * 16);
            *(uint4*)((char*)g0 + (size_t)nb * 256 + c * 16) = *(uint4*)((char*)gbuf + c * 16);
        }
    }
}

// ---------------- GCNII layer ----------------
// gather v2: one 16-lane group owns one node (lane sub = features sub*8..+7).
//   - block's col slice + rowp window staged in LDS (coalesced)
//   - dynamic work-stealing over the 32 nodes via LDS counter
//   - 4 independent row loads in flight, no shuffles
// GEMM: MFMA on f16 comb (csh swizzled), exact f32 comb kept in cs for epilogue.
// OUT_MODE 0: gOut = f16(dinv*h)   OUT_MODE 1: hOut = f32 h (last layer)

template <int OUT_MODE>
__global__ __launch_bounds__(256) void k_layer(const __half2* __restrict__ gIn,
                                               __half* __restrict__ gOutH,
                                               float* __restrict__ hOut,
                                               const __half2* __restrict__ h0,
                                               const float* __restrict__ dinv,
                                               const int* __restrict__ rowp,
                                               const int* __restrict__ col,
                                               const __half* __restrict__ wfL,
                                               float beta) {
    __shared__ float cs[NPB * HD];      // 16 KB: comb rows (f32, linear)
    __shared__ __half csh[NPB * HD];    // 8 KB: comb f16, swizzled; reused for output
    __shared__ int sCol[ECAP];          // 3 KB staged col indices
    __shared__ int sRowp[NPB + 1];
    __shared__ int sCtr;
    int tid = threadIdx.x;
    int nb = blockIdx.x * NPB;
    int lane = tid & 63;
    int sub = lane & 15;                // lane within 16-lane group
    const uint4* g4 = (const uint4*)gIn;   // 16 chunks of 16B per row
    const uint4* h4 = (const uint4*)h0;

    if (tid == 0) sCtr = 0;
    if (tid <= NPB) sRowp[tid] = rowp[nb + tid];
    __syncthreads();
    int base = sRowp[0];
    int total = sRowp[NPB] - base;
    int stct = total < ECAP ? total : ECAP;
    for (int i = tid; i < stct; i += 256) sCol[i] = col[base + i];
    __syncthreads();

    while (true) {
        int nl;
        if (sub == 0) nl = atomicAdd(&sCtr, 1);
        nl = __shfl(nl, lane & 48);     // broadcast from group leader
        if (nl >= NPB) break;
        int n = nb + nl;
        int beg = sRowp[nl] - base, end = sRowp[nl + 1] - base;

        // self-loop init
        float acc[8];
        {
            U16 v; v.u = g4[(size_t)n * 16 + sub];
#pragma unroll
            for (int q = 0; q < 4; q++) {
                float2 f = __half22float2(v.h2[q]);
                acc[2 * q] = f.x; acc[2 * q + 1] = f.y;
            }
        }

        int e = beg;
        for (; e + 4 <= end; e += 4) {
            int c0 = (e     < ECAP) ? sCol[e]     : col[base + e];
            int c1 = (e + 1 < ECAP) ? sCol[e + 1] : col[base + e + 1];
            int c2 = (e + 2 < ECAP) ? sCol[e + 2] : col[base + e + 2];
            int c3 = (e + 3 < ECAP) ? sCol[e + 3] : col[base + e + 3];
            U16 a0, a1, a2, a3;
            a0.u = g4[(size_t)c0 * 16 + sub];
            a1.u = g4[(size_t)c1 * 16 + sub];
            a2.u = g4[(size_t)c2 * 16 + sub];
            a3.u = g4[(size_t)c3 * 16 + sub];
#pragma unroll
            for (int q = 0; q < 4; q++) {
                float2 f0 = __half22float2(a0.h2[q]);
                float2 f1 = __half22float2(a1.h2[q]);
                float2 f2 = __half22float2(a2.h2[q]);
                float2 f3 = __half22float2(a3.h2[q]);
                acc[2 * q]     += (f0.x + f1.x) + (f2.x + f3.x);
                acc[2 * q + 1] += (f0.y + f1.y) + (f2.y + f3.y);
            }
        }
        if (e + 2 <= end) {
            int c0 = (e     < ECAP) ? sCol[e]     : col[base + e];
            int c1 = (e + 1 < ECAP) ? sCol[e + 1] : col[base + e + 1];
            U16 a0, a1;
            a0.u = g4[(size_t)c0 * 16 + sub];
            a1.u = g4[(size_t)c1 * 16 + sub];
#pragma unroll
            for (int q = 0; q < 4; q++) {
                float2 f0 = __half22float2(a0.h2[q]);
                float2 f1 = __half22float2(a1.h2[q]);
                acc[2 * q]     += f0.x + f1.x;
                acc[2 * q + 1] += f0.y + f1.y;
            }
            e += 2;
        }
        if (e < end) {
            int c0 = (e < ECAP) ? sCol[e] : col[base + e];
            U16 a0; a0.u = g4[(size_t)c0 * 16 + sub];
#pragma unroll
            for (int q = 0; q < 4; q++) {
                float2 f0 = __half22float2(a0.h2[q]);
                acc[2 * q] += f0.x; acc[2 * q + 1] += f0.y;
            }
        }

        float dv = dinv[n];
        U16 hv; hv.u = h4[(size_t)n * 16 + sub];
        float co[8];
        U16 p;
#pragma unroll
        for (int q = 0; q < 4; q++) {
            float2 hf = __half22float2(hv.h2[q]);
            co[2 * q]     = 0.9f * dv * acc[2 * q]     + 0.1f * hf.x;
            co[2 * q + 1] = 0.9f * dv * acc[2 * q + 1] + 0.1f * hf.y;
            p.h2[q] = __float22half2_rn(make_float2(co[2 * q], co[2 * q + 1]));
        }
        *(float4*)&cs[nl * HD + sub * 8]     = make_float4(co[0], co[1], co[2], co[3]);
        *(float4*)&cs[nl * HD + sub * 8 + 4] = make_float4(co[4], co[5], co[6], co[7]);
        int fbyte = (nl * 256 + sub * 16) ^ ((nl & 7) << 4);
        *(uint4*)((char*)csh + fbyte) = p.u;
    }
    __syncthreads();

    // MFMA GEMM: 2 row-tiles x 8 col-tiles, 4 tiles/wave
    int wave = tid >> 6;
    int rt = wave >> 1;
    int ntb = (wave & 1) * 4;
    int arow = rt * 16 + (lane & 15);
    f16x8 a[4];
#pragma unroll
    for (int ks = 0; ks < 4; ks++) {
        int byte = (arow * 256 + ks * 64 + (lane >> 4) * 16) ^ ((arow & 7) << 4);
        U16 r; r.u = *(const uint4*)((const char*)csh + byte);
        a[ks] = r.v;
    }
    __syncthreads();   // a-frags in regs; csh reusable as output buffer

    const uint4* bf = (const uint4*)wfL;
    float omb = 1.f - beta;
#pragma unroll
    for (int nt2 = 0; nt2 < 4; nt2++) {
        int nt = ntb + nt2;
        f32x4 acc = {0.f, 0.f, 0.f, 0.f};
#pragma unroll
        for (int ks = 0; ks < 4; ks++) {
            U16 bw; bw.u = bf[(nt * 4 + ks) * 64 + lane];
            acc = __builtin_amdgcn_mfma_f32_16x16x32_f16(a[ks], bw.v, acc, 0, 0, 0);
        }
        int colb = nt * 16 + (lane & 15);
#pragma unroll
        for (int r = 0; r < 4; r++) {
            int row = rt * 16 + (lane >> 4) * 4 + r;
            int gn = nb + row;
            float comb = cs[row * HD + colb];
            float v = fmaxf(omb * comb + beta * acc[r], 0.f);
            if (OUT_MODE == 0) {
                csh[row * HD + colb] = __float2half(dinv[gn] * v);
            } else {
                hOut[(size_t)gn * HD + colb] = v;
            }
        }
    }
    if (OUT_MODE == 0) {
        __syncthreads();
        // coalesced copy-out: 32 rows x 256B = 512 chunks of 16B
#pragma unroll
        for (int it = 0; it < 2; it++) {
            int c = it * 256 + tid;
            *(uint4*)((char*)gOutH + (size_t)nb * 256 + c * 16) =
                *(uint4*)((char*)csh + c * 16);
        }
    }
}

// ---------------- final (MFMA): out = h@W2+b2; vis = relu(out@Wv+bv); txt = relu(out@Wt+bt)

__global__ __launch_bounds__(256) void k_final(const float* __restrict__ hIn,
                                               const __half* __restrict__ wf,
                                               const float* __restrict__ b2,
                                               const float* __restrict__ bv,
                                               const float* __restrict__ bt,
                                               float* __restrict__ out,
                                               float* __restrict__ vis,
                                               float* __restrict__ txt) {
    __shared__ __half hs[FNPB * HD];  // 16 KB, XOR-swizzled rows
    __shared__ __half os[FNPB * HD];  // 16 KB, XOR-swizzled rows
    int tid = threadIdx.x;
    int nb = blockIdx.x * FNPB;
    int wave = tid >> 6, lane = tid & 63;

    // stage h rows as swizzled f16
#pragma unroll
    for (int it = 0; it < 4; it++) {
        int idx8 = it * 256 + tid;            // chunk of 8 floats; 64 rows x 16 chunks
        int row = idx8 >> 4, c8 = idx8 & 15;
        int gn = nb + row;
        float4 a = make_float4(0.f, 0.f, 0.f, 0.f), b = a;
        if (gn < NN) {
            a = *(const float4*)&hIn[(size_t)gn * HD + c8 * 8];
            b = *(const float4*)&hIn[(size_t)gn * HD + c8 * 8 + 4];
        }
        U16 p;
        p.h[0] = __float2half(a.x); p.h[1] = __float2half(a.y);
        p.h[2] = __float2half(a.z); p.h[3] = __float2half(a.w);
        p.h[4] = __float2half(b.x); p.h[5] = __float2half(b.y);
        p.h[6] = __float2half(b.z); p.h[7] = __float2half(b.w);
        int byte = (row * 256 + c8 * 16) ^ ((row & 7) << 4);
        *(uint4*)((char*)hs + byte) = p.u;
    }
    __syncthreads();

    const uint4* bf2 = (const uint4*)(wf + (size_t)8 * HD * HD);
    const uint4* bfv = (const uint4*)(wf + (size_t)9 * HD * HD);
    const uint4* bft = (const uint4*)(wf + (size_t)10 * HD * HD);

    int arow = wave * 16 + (lane & 15);
    int kb = (lane >> 4) * 8;

    // A-frags from hs
    f16x8 a[4];
#pragma unroll
    for (int ks = 0; ks < 4; ks++) {
        int byte = (arow * 256 + (ks * 32 + kb) * 2) ^ ((arow & 7) << 4);
        U16 r; r.u = *(const uint4*)((const char*)hs + byte);
        a[ks] = r.v;
    }

    // GEMM1: out = h@W2 + b2 ; also write f16 copy into os
#pragma unroll
    for (int nt = 0; nt < 8; nt++) {
        f32x4 acc = {0.f, 0.f, 0.f, 0.f};
#pragma unroll
        for (int ks = 0; ks < 4; ks++) {
            U16 bw; bw.u = bf2[(nt * 4 + ks) * 64 + lane];
            acc = __builtin_amdgcn_mfma_f32_16x16x32_f16(a[ks], bw.v, acc, 0, 0, 0);
        }
        int c = nt * 16 + (lane & 15);
        float bias = b2[c];
#pragma unroll
        for (int r = 0; r < 4; r++) {
            int lrow = wave * 16 + (lane >> 4) * 4 + r;
            float val = acc[r] + bias;
            int gn = nb + lrow;
            if (gn < NN) out[(size_t)gn * HD + c] = val;
            int byte = (lrow * 256 + c * 2) ^ ((lrow & 7) << 4);
            *(__half*)((char*)os + byte) = __float2half(val);
        }
    }
    __syncthreads();

    // A-frags from os
    f16x8 ao[4];
#pragma unroll
    for (int ks = 0; ks < 4; ks++) {
        int byte = (arow * 256 + (ks * 32 + kb) * 2) ^ ((arow & 7) << 4);
        U16 r; r.u = *(const uint4*)((const char*)os + byte);
        ao[ks] = r.v;
    }

    // GEMM2: vis = relu(out@Wv+bv); GEMM3: txt = relu(out@Wt+bt)
#pragma unroll
    for (int nt = 0; nt < 8; nt++) {
        f32x4 accv = {0.f, 0.f, 0.f, 0.f};
        f32x4 acct = {0.f, 0.f, 0.f, 0.f};
#pragma unroll
        for (int ks = 0; ks < 4; ks++) {
            U16 bwv; bwv.u = bfv[(nt * 4 + ks) * 64 + lane];
            U16 bwt; bwt.u = bft[(nt * 4 + ks) * 64 + lane];
            accv = __builtin_amdgcn_mfma_f32_16x16x32_f16(ao[ks], bwv.v, accv, 0, 0, 0);
            acct = __builtin_amdgcn_mfma_f32_16x16x32_f16(ao[ks], bwt.v, acct, 0, 0, 0);
        }
        int c = nt * 16 + (lane & 15);
        float biasv = bv[c], biast = bt[c];
#pragma unroll
        for (int r = 0; r < 4; r++) {
            int lrow = wave * 16 + (lane >> 4) * 4 + r;
            int gn = nb + lrow;
            if (gn < NN) {
                vis[(size_t)gn * HD + c] = fmaxf(accv[r] + biasv, 0.f);
                txt[(size_t)gn * HD + c] = fmaxf(acct[r] + biast, 0.f);
            }
        }
    }
}

// ---------------- launch ----------------

extern "C" void kernel_launch(void* const* d_in, const int* in_sizes, int n_in,
                              void* d_out, int out_size, void* d_ws, size_t ws_size,
                              hipStream_t stream) {
    (void)in_sizes; (void)n_in; (void)out_size; (void)ws_size;

    const float* x    = (const float*)d_in[0];
    const int*   edge = (const int*)d_in[1];   // [2,E]: src then dst
    const float* W1   = (const float*)d_in[2];
    const float* b1   = (const float*)d_in[3];
    const float* cw   = (const float*)d_in[4]; // [8,128,128]
    const float* W2   = (const float*)d_in[5];
    const float* b2   = (const float*)d_in[6];
    const float* Wv   = (const float*)d_in[7];
    const float* bv   = (const float*)d_in[8];
    const float* Wt   = (const float*)d_in[9];
    const float* bt   = (const float*)d_in[10];

    const int* esrc = edge;
    const int* edst = edge + NE;

    // d_out regions: [0]=h(f32, layer7 out) then `out`; [1]=h0(f16) then vis;
    // [2]=g ping-pong (2 x f16) then txt
    float* out0 = (float*)d_out;
    float* reg1 = out0 + (size_t)NN * HD;
    float* reg2 = reg1 + (size_t)NN * HD;

    __half* h0h = (__half*)reg1;
    __half* ga  = (__half*)reg2;
    __half* gb  = (__half*)((char*)reg2 + H16_BYTES);

    // workspace layout
    char* ws = (char*)d_ws;
    int*   deg_i = (int*)(ws + 0);          // N ints
    int*   fill  = (int*)(ws + 400000);     // N ints
    int*   rowp  = (int*)(ws + 800000);     // N+1 ints
    int*   bsums = (int*)(ws + 1200128);    // 128 ints
    int*   col   = (int*)(ws + 1200640);    // E ints
    float* dinv  = (float*)(ws + 5200640);  // N floats
    __half* wf   = (__half*)(ws + 5600640); // 11 * 128*128 halfs = 360448 B
    __half* w1f  = (__half*)(ws + 5961088); // 256*128 halfs = 65536 B

    hipMemsetAsync(ws, 0, 800000, stream);  // deg_i + fill

    k_deg<<<(NE + 255) / 256, 256, 0, stream>>>(edst, deg_i);
    k_dinv<<<(NN + 255) / 256, 256, 0, stream>>>(deg_i, dinv);
    k_scan1<<<NBLK_SCAN, 1024, 0, stream>>>(deg_i, rowp, bsums);
    k_scan2<<<1, 128, 0, stream>>>(bsums);
    k_scan3<<<NBLK_SCAN, 1024, 0, stream>>>(rowp, bsums);
    k_fill<<<(NE + 255) / 256, 256, 0, stream>>>(esrc, edst, rowp, fill, col);
    k_wfrag<<<11 * 16, 256, 0, stream>>>(cw, W2, Wv, Wt, wf);
    k_w1frag<<<32, 256, 0, stream>>>(W1, w1f);

    k_init<<<(NN + INPB - 1) / INPB, 256, 0, stream>>>(x, w1f, b1, dinv, h0h, ga);

    // layers 0..6: f16 ping-pong (l even: ga->gb, odd: gb->ga). After l=6, g in gb.
    for (int l = 0; l < 7; l++) {
        float beta = (float)log(0.5 / (double)(l + 1) + 1.0);
        const __half* gi = (l & 1) ? gb : ga;
        __half*       go = (l & 1) ? ga : gb;
        k_layer<0><<<NN / NPB, 256, 0, stream>>>((const __half2*)gi, go,
                                                 (float*)nullptr, (const __half2*)h0h,
                                                 dinv, rowp, col,
                                                 wf + (size_t)l * HD * HD, beta);
    }
    // layer 7: gb -> f32 h in region0
    {
        float beta = (float)log(0.5 / 8.0 + 1.0);
        k_layer<1><<<NN / NPB, 256, 0, stream>>>((const __half2*)gb, (__half*)nullptr,
                                                 out0, (const __half2*)h0h,
                                                 dinv, rowp, col,
                                                 wf + (size_t)7 * HD * HD, beta);
    }

    k_final<<<(NN + FNPB - 1) / FNPB, 256, 0, stream>>>(out0, wf, b2, bv, bt,
                                                        out0, reg1, reg2);
}

// Round 6
// 612.061 us; speedup vs baseline: 2.9381x; 1.0450x over previous
//
#include <hip/hip_runtime.h>
#include <hip/hip_fp16.h>
#include <math.h>

#define NN 100000
#define NE 1000000
#define IND 256
#define HD  128
#define HD2 64           // half2 elements per row
#define NPB 32           // nodes per block in layer kernel
#define FNPB 64          // nodes per block in final kernel
#define INPB 64          // nodes per block in init kernel
#define NBLK_SCAN 98     // ceil(NN/1024)
#define ECAP 768         // staged edges per block (avg 320, Poisson tail-safe + guarded)
#define H16_BYTES ((size_t)NN * HD * 2)   // 25,600,000

typedef _Float16 f16x8 __attribute__((ext_vector_type(8)));
typedef float f32x4 __attribute__((ext_vector_type(4)));

union U16 { uint4 u; __half2 h2[4]; __half h[8]; f16x8 v; };

// ---------------- CSR build ----------------

__global__ __launch_bounds__(256) void k_deg(const int* __restrict__ dst,
                                             int* __restrict__ deg) {
    int e = blockIdx.x * 256 + threadIdx.x;
    if (e < NE) atomicAdd(&deg[dst[e]], 1);
}

__global__ __launch_bounds__(256) void k_dinv(const int* __restrict__ deg,
                                              float* __restrict__ dinv) {
    int i = blockIdx.x * 256 + threadIdx.x;
    if (i < NN) dinv[i] = rsqrtf((float)(deg[i] + 1));  // +1 self-loop
}

__global__ __launch_bounds__(1024) void k_scan1(const int* __restrict__ deg,
                                                int* __restrict__ rowp,
                                                int* __restrict__ bsums) {
    __shared__ int s[1024];
    int t = threadIdx.x;
    int i = blockIdx.x * 1024 + t;
    int v = (i < NN) ? deg[i] : 0;
    s[t] = v;
    __syncthreads();
    for (int off = 1; off < 1024; off <<= 1) {
        int u = (t >= off) ? s[t - off] : 0;
        __syncthreads();
        s[t] += u;
        __syncthreads();
    }
    if (i < NN) rowp[i] = s[t] - v;
    if (t == 1023) bsums[blockIdx.x] = s[1023];
}

__global__ __launch_bounds__(128) void k_scan2(int* __restrict__ bsums) {
    __shared__ int s[128];
    int t = threadIdx.x;
    int v = (t < NBLK_SCAN) ? bsums[t] : 0;
    s[t] = v;
    __syncthreads();
    for (int off = 1; off < 128; off <<= 1) {
        int u = (t >= off) ? s[t - off] : 0;
        __syncthreads();
        s[t] += u;
        __syncthreads();
    }
    if (t < NBLK_SCAN) bsums[t] = s[t] - v;
}

__global__ __launch_bounds__(1024) void k_scan3(int* __restrict__ rowp,
                                                const int* __restrict__ bsums) {
    int i = blockIdx.x * 1024 + threadIdx.x;
    if (i < NN) rowp[i] += bsums[i >> 10];
    if (i == 0) rowp[NN] = NE;
}

__global__ __launch_bounds__(256) void k_fill(const int* __restrict__ src,
                                              const int* __restrict__ dst,
                                              const int* __restrict__ rowp,
                                              int* __restrict__ fill,
                                              int* __restrict__ col) {
    int e = blockIdx.x * 256 + threadIdx.x;
    if (e < NE) {
        int d = dst[e];
        int pos = rowp[d] + atomicAdd(&fill[d], 1);
        col[pos] = src[e];
    }
}

// ---------------- weight fragment pre-pack ----------------
// KS=4 layout: wf[m][((nt*4+ks)*64+lane)*8+j] = f16(W'[ks*32+(lane>>4)*8+j][nt*16+(lane&15)])
// For m<8 (conv layers) the residual is folded in: W' = beta*W + (1-beta)*I.

__global__ __launch_bounds__(256) void k_wfrag(const float* __restrict__ cw,
                                               const float* __restrict__ W2,
                                               const float* __restrict__ Wv,
                                               const float* __restrict__ Wt,
                                               __half* __restrict__ wf) {
    int m = blockIdx.x >> 4;     // matrix 0..10
    int blk = blockIdx.x & 15;
    const float* W = (m < 8) ? (cw + (size_t)m * HD * HD)
                             : (m == 8 ? W2 : (m == 9 ? Wv : Wt));
    int i = (blk * 256 + threadIdx.x) * 4;   // element index k*128+col
    float4 v = *(const float4*)&W[i];
    int k = i >> 7, col0 = i & 127;
    float vv[4] = {v.x, v.y, v.z, v.w};
    float beta = 1.f, omb = 0.f;
    if (m < 8) {
        beta = logf(0.5f / (float)(m + 1) + 1.0f);
        omb = 1.f - beta;
    }
    __half* dstm = wf + (size_t)m * HD * HD;
    int ks = k >> 5, laneK = ((k >> 3) & 3) * 16, j = k & 7;
#pragma unroll
    for (int t = 0; t < 4; t++) {
        int col = col0 + t;
        float val = beta * vv[t] + ((k == col) ? omb : 0.f);
        int nt = col >> 4;
        int lane = laneK + (col & 15);
        dstm[((nt * 4 + ks) * 64 + lane) * 8 + j] = __float2half(val);
    }
}

// W1 [256,128], KS=8: w1f[((nt*8+ks)*64+lane)*8+j] = f16(W1[ks*32+(lane>>4)*8+j][nt*16+(lane&15)])

__global__ __launch_bounds__(256) void k_w1frag(const float* __restrict__ W1,
                                                __half* __restrict__ w1f) {
    int i = (blockIdx.x * 256 + threadIdx.x) * 4;   // k*128+col, total 32768
    float4 v = *(const float4*)&W1[i];
    int k = i >> 7, col0 = i & 127;
    float vv[4] = {v.x, v.y, v.z, v.w};
    int ks = k >> 5, laneK = ((k >> 3) & 3) * 16, j = k & 7;
#pragma unroll
    for (int t = 0; t < 4; t++) {
        int col = col0 + t;
        int nt = col >> 4;
        int lane = laneK + (col & 15);
        w1f[((nt * 8 + ks) * 64 + lane) * 8 + j] = __float2half(vv[t]);
    }
}

// ---------------- initial transform (MFMA): h0 = relu(x@W1+b1) f16, g0 = dinv*h0 f16 ----

__global__ __launch_bounds__(256) void k_init(const float* __restrict__ x,
                                              const __half* __restrict__ w1f,
                                              const float* __restrict__ b1,
                                              const float* __restrict__ dinv,
                                              __half* __restrict__ h0h,
                                              __half* __restrict__ g0) {
    __shared__ char lds[32768];     // xs (swizzled f16 64x256), later hb/gb
    int tid = threadIdx.x;
    int nb = blockIdx.x * INPB;
    int wv = tid >> 6, lane = tid & 63;

    // stage x -> f16 swizzled (rows of 512B)
#pragma unroll
    for (int it = 0; it < 8; it++) {
        int c = it * 256 + tid;          // chunk of 8 floats: 64 rows x 32 chunks
        int row = c >> 5, k8 = c & 31;
        int gn = nb + row;
        float4 a = make_float4(0.f, 0.f, 0.f, 0.f), b = a;
        if (gn < NN) {
            a = *(const float4*)&x[(size_t)gn * IND + k8 * 8];
            b = *(const float4*)&x[(size_t)gn * IND + k8 * 8 + 4];
        }
        U16 p;
        p.h[0] = __float2half(a.x); p.h[1] = __float2half(a.y);
        p.h[2] = __float2half(a.z); p.h[3] = __float2half(a.w);
        p.h[4] = __float2half(b.x); p.h[5] = __float2half(b.y);
        p.h[6] = __float2half(b.z); p.h[7] = __float2half(b.w);
        int byte = (row * 512 + k8 * 16) ^ ((row & 7) << 4);
        *(uint4*)(lds + byte) = p.u;
    }
    __syncthreads();

    // A-frags: wave = row-tile
    int arow = wv * 16 + (lane & 15);
    f16x8 a[8];
#pragma unroll
    for (int ks = 0; ks < 8; ks++) {
        int byte = (arow * 512 + ks * 64 + (lane >> 4) * 16) ^ ((arow & 7) << 4);
        U16 r; r.u = *(const uint4*)(lds + byte);
        a[ks] = r.v;
    }
    __syncthreads();   // all waves done reading xs before epilogue overwrites

    __half* hb = (__half*)lds;            // 64x128 f16 linear
    __half* gbuf = (__half*)(lds + 16384);
    const uint4* bf = (const uint4*)w1f;

#pragma unroll
    for (int nt = 0; nt < 8; nt++) {
        f32x4 acc = {0.f, 0.f, 0.f, 0.f};
#pragma unroll
        for (int ks = 0; ks < 8; ks++) {
            U16 bw; bw.u = bf[(nt * 8 + ks) * 64 + lane];
            acc = __builtin_amdgcn_mfma_f32_16x16x32_f16(a[ks], bw.v, acc, 0, 0, 0);
        }
        int colb = nt * 16 + (lane & 15);
        float bias = b1[colb];
#pragma unroll
        for (int r = 0; r < 4; r++) {
            int row = wv * 16 + (lane >> 4) * 4 + r;
            int gn = nb + row;
            float dv = (gn < NN) ? dinv[gn] : 0.f;
            float v = fmaxf(acc[r] + bias, 0.f);
            hb[row * HD + colb] = __float2half(v);
            gbuf[row * HD + colb] = __float2half(dv * v);
        }
    }
    __syncthreads();

    // coalesced copy-out
#pragma unroll
    for (int it = 0; it < 4; it++) {
        int c = it * 256 + tid;          // 1024 chunks of 16B per buffer
        int row = c >> 4;
        if (nb + row < NN) {
            *(uint4*)((char*)h0h + (size_t)nb * 256 + c * 16) = *(uint4*)((char*)hb + c * 16);
            *(uint4*)((char*)g0 + (size_t)nb * 256 + c * 16) = *(uint4*)((char*)gbuf + c * 16);
        }
    }
}

// ---------------- GCNII layer ----------------
// gather: one 16-lane group owns one node; col slice staged in LDS; work-stealing.
// GEMM: h = relu(comb @ W') with W' = (1-b)I + bW pre-folded -> no f32 comb needed.
// OUT_MODE 0: gOut = f16(dinv*h) contiguous   OUT_MODE 1: hOut = f16 h, 512B-strided

template <int OUT_MODE>
__global__ __launch_bounds__(256) void k_layer(const __half2* __restrict__ gIn,
                                               __half* __restrict__ gOutH,
                                               __half* __restrict__ hOut7,
                                               const __half2* __restrict__ h0,
                                               const float* __restrict__ dinv,
                                               const int* __restrict__ rowp,
                                               const int* __restrict__ col,
                                               const __half* __restrict__ wfL) {
    __shared__ __half csh[NPB * HD];    // 8 KB: comb f16, swizzled; reused for output
    __shared__ int sCol[ECAP];          // 3 KB staged col indices
    __shared__ int sRowp[NPB + 1];
    __shared__ int sCtr;
    int tid = threadIdx.x;
    int nb = blockIdx.x * NPB;
    int lane = tid & 63;
    int sub = lane & 15;                // lane within 16-lane group
    const uint4* g4 = (const uint4*)gIn;   // 16 chunks of 16B per row
    const uint4* h4 = (const uint4*)h0;

    if (tid == 0) sCtr = 0;
    if (tid <= NPB) sRowp[tid] = rowp[nb + tid];
    __syncthreads();
    int base = sRowp[0];
    int total = sRowp[NPB] - base;
    int stct = total < ECAP ? total : ECAP;
    for (int i = tid; i < stct; i += 256) sCol[i] = col[base + i];
    __syncthreads();

    while (true) {
        int nl;
        if (sub == 0) nl = atomicAdd(&sCtr, 1);
        nl = __shfl(nl, lane & 48);     // broadcast from group leader
        if (nl >= NPB) break;
        int n = nb + nl;
        int beg = sRowp[nl] - base, end = sRowp[nl + 1] - base;

        // self-loop init
        float acc[8];
        {
            U16 v; v.u = g4[(size_t)n * 16 + sub];
#pragma unroll
            for (int q = 0; q < 4; q++) {
                float2 f = __half22float2(v.h2[q]);
                acc[2 * q] = f.x; acc[2 * q + 1] = f.y;
            }
        }

        int e = beg;
        for (; e + 4 <= end; e += 4) {
            int c0 = (e     < ECAP) ? sCol[e]     : col[base + e];
            int c1 = (e + 1 < ECAP) ? sCol[e + 1] : col[base + e + 1];
            int c2 = (e + 2 < ECAP) ? sCol[e + 2] : col[base + e + 2];
            int c3 = (e + 3 < ECAP) ? sCol[e + 3] : col[base + e + 3];
            U16 a0, a1, a2, a3;
            a0.u = g4[(size_t)c0 * 16 + sub];
            a1.u = g4[(size_t)c1 * 16 + sub];
            a2.u = g4[(size_t)c2 * 16 + sub];
            a3.u = g4[(size_t)c3 * 16 + sub];
#pragma unroll
            for (int q = 0; q < 4; q++) {
                float2 f0 = __half22float2(a0.h2[q]);
                float2 f1 = __half22float2(a1.h2[q]);
                float2 f2 = __half22float2(a2.h2[q]);
                float2 f3 = __half22float2(a3.h2[q]);
                acc[2 * q]     += (f0.x + f1.x) + (f2.x + f3.x);
                acc[2 * q + 1] += (f0.y + f1.y) + (f2.y + f3.y);
            }
        }
        if (e + 2 <= end) {
            int c0 = (e     < ECAP) ? sCol[e]     : col[base + e];
            int c1 = (e + 1 < ECAP) ? sCol[e + 1] : col[base + e + 1];
            U16 a0, a1;
            a0.u = g4[(size_t)c0 * 16 + sub];
            a1.u = g4[(size_t)c1 * 16 + sub];
#pragma unroll
            for (int q = 0; q < 4; q++) {
                float2 f0 = __half22float2(a0.h2[q]);
                float2 f1 = __half22float2(a1.h2[q]);
                acc[2 * q]     += f0.x + f1.x;
                acc[2 * q + 1] += f0.y + f1.y;
            }
            e += 2;
        }
        if (e < end) {
            int c0 = (e < ECAP) ? sCol[e] : col[base + e];
            U16 a0; a0.u = g4[(size_t)c0 * 16 + sub];
#pragma unroll
            for (int q = 0; q < 4; q++) {
                float2 f0 = __half22float2(a0.h2[q]);
                acc[2 * q] += f0.x; acc[2 * q + 1] += f0.y;
            }
        }

        float dv = dinv[n];
        U16 hv; hv.u = h4[(size_t)n * 16 + sub];
        U16 p;
#pragma unroll
        for (int q = 0; q < 4; q++) {
            float2 hf = __half22float2(hv.h2[q]);
            float c0 = 0.9f * dv * acc[2 * q]     + 0.1f * hf.x;
            float c1 = 0.9f * dv * acc[2 * q + 1] + 0.1f * hf.y;
            p.h2[q] = __float22half2_rn(make_float2(c0, c1));
        }
        int fbyte = (nl * 256 + sub * 16) ^ ((nl & 7) << 4);
        *(uint4*)((char*)csh + fbyte) = p.u;
    }
    __syncthreads();

    // MFMA GEMM: 2 row-tiles x 8 col-tiles, 4 tiles/wave; h = relu(comb @ W')
    int wave = tid >> 6;
    int rt = wave >> 1;
    int ntb = (wave & 1) * 4;
    int arow = rt * 16 + (lane & 15);
    f16x8 a[4];
#pragma unroll
    for (int ks = 0; ks < 4; ks++) {
        int byte = (arow * 256 + ks * 64 + (lane >> 4) * 16) ^ ((arow & 7) << 4);
        U16 r; r.u = *(const uint4*)((const char*)csh + byte);
        a[ks] = r.v;
    }
    __syncthreads();   // a-frags in regs; csh reusable as output buffer

    const uint4* bf = (const uint4*)wfL;
#pragma unroll
    for (int nt2 = 0; nt2 < 4; nt2++) {
        int nt = ntb + nt2;
        f32x4 acc = {0.f, 0.f, 0.f, 0.f};
#pragma unroll
        for (int ks = 0; ks < 4; ks++) {
            U16 bw; bw.u = bf[(nt * 4 + ks) * 64 + lane];
            acc = __builtin_amdgcn_mfma_f32_16x16x32_f16(a[ks], bw.v, acc, 0, 0, 0);
        }
        int colb = nt * 16 + (lane & 15);
#pragma unroll
        for (int r = 0; r < 4; r++) {
            int row = rt * 16 + (lane >> 4) * 4 + r;
            int gn = nb + row;
            float v = fmaxf(acc[r], 0.f);
            if (OUT_MODE == 0) {
                csh[row * HD + colb] = __float2half(dinv[gn] * v);
            } else {
                csh[row * HD + colb] = __float2half(v);
            }
        }
    }
    __syncthreads();
    // coalesced copy-out: 32 rows x 256B = 512 chunks of 16B
    if (OUT_MODE == 0) {
#pragma unroll
        for (int it = 0; it < 2; it++) {
            int c = it * 256 + tid;
            *(uint4*)((char*)gOutH + (size_t)nb * 256 + c * 16) =
                *(uint4*)((char*)csh + c * 16);
        }
    } else {
        // strided: row gn occupies first 256B of a 512B slot (1:1 with k_final blocks)
#pragma unroll
        for (int it = 0; it < 2; it++) {
            int c = it * 256 + tid;
            int row = c >> 4;
            *(uint4*)((char*)hOut7 + ((size_t)(nb + row) * 512 + (c & 15) * 16)) =
                *(uint4*)((char*)csh + c * 16);
        }
    }
}

// ---------------- final (MFMA): out = h@W2+b2; vis = relu(out@Wv+bv); txt = relu(out@Wt+bt)
// hIn: f16 rows strided at 512B (first 256B of each slot), co-located with `out`.

__global__ __launch_bounds__(256) void k_final(const __half* __restrict__ hIn,
                                               const __half* __restrict__ wf,
                                               const float* __restrict__ b2,
                                               const float* __restrict__ bv,
                                               const float* __restrict__ bt,
                                               float* __restrict__ out,
                                               float* __restrict__ vis,
                                               float* __restrict__ txt) {
    __shared__ __half hs[FNPB * HD];  // 16 KB, XOR-swizzled rows
    __shared__ __half os[FNPB * HD];  // 16 KB, XOR-swizzled rows
    int tid = threadIdx.x;
    int nb = blockIdx.x * FNPB;
    int wave = tid >> 6, lane = tid & 63;

    // stage h rows (f16, strided in global) -> swizzled LDS
#pragma unroll
    for (int it = 0; it < 4; it++) {
        int idx = it * 256 + tid;            // 16B chunk; 64 rows x 16 chunks
        int row = idx >> 4, c8 = idx & 15;
        int gn = nb + row;
        uint4 p = make_uint4(0, 0, 0, 0);
        if (gn < NN)
            p = *(const uint4*)((const char*)hIn + (size_t)gn * 512 + c8 * 16);
        int byte = (row * 256 + c8 * 16) ^ ((row & 7) << 4);
        *(uint4*)((char*)hs + byte) = p;
    }
    __syncthreads();

    const uint4* bf2 = (const uint4*)(wf + (size_t)8 * HD * HD);
    const uint4* bfv = (const uint4*)(wf + (size_t)9 * HD * HD);
    const uint4* bft = (const uint4*)(wf + (size_t)10 * HD * HD);

    int arow = wave * 16 + (lane & 15);
    int kb = (lane >> 4) * 8;

    // A-frags from hs
    f16x8 a[4];
#pragma unroll
    for (int ks = 0; ks < 4; ks++) {
        int byte = (arow * 256 + (ks * 32 + kb) * 2) ^ ((arow & 7) << 4);
        U16 r; r.u = *(const uint4*)((const char*)hs + byte);
        a[ks] = r.v;
    }

    // GEMM1: out = h@W2 + b2 ; also write f16 copy into os
#pragma unroll
    for (int nt = 0; nt < 8; nt++) {
        f32x4 acc = {0.f, 0.f, 0.f, 0.f};
#pragma unroll
        for (int ks = 0; ks < 4; ks++) {
            U16 bw; bw.u = bf2[(nt * 4 + ks) * 64 + lane];
            acc = __builtin_amdgcn_mfma_f32_16x16x32_f16(a[ks], bw.v, acc, 0, 0, 0);
        }
        int c = nt * 16 + (lane & 15);
        float bias = b2[c];
#pragma unroll
        for (int r = 0; r < 4; r++) {
            int lrow = wave * 16 + (lane >> 4) * 4 + r;
            float val = acc[r] + bias;
            int gn = nb + lrow;
            if (gn < NN) out[(size_t)gn * HD + c] = val;
            int byte = (lrow * 256 + c * 2) ^ ((lrow & 7) << 4);
            *(__half*)((char*)os + byte) = __float2half(val);
        }
    }
    __syncthreads();

    // A-frags from os
    f16x8 ao[4];
#pragma unroll
    for (int ks = 0; ks < 4; ks++) {
        int byte = (arow * 256 + (ks * 32 + kb) * 2) ^ ((arow & 7) << 4);
        U16 r; r.u = *(const uint4*)((const char*)os + byte);
        ao[ks] = r.v;
    }

    // GEMM2: vis = relu(out@Wv+bv); GEMM3: txt = relu(out@Wt+bt)
#pragma unroll
    for (int nt = 0; nt < 8; nt++) {
        f32x4 accv = {0.f, 0.f, 0.f, 0.f};
        f32x4 acct = {0.f, 0.f, 0.f, 0.f};
#pragma unroll
        for (int ks = 0; ks < 4; ks++) {
            U16 bwv; bwv.u = bfv[(nt * 4 + ks) * 64 + lane];
            U16 bwt; bwt.u = bft[(nt * 4 + ks) * 64 + lane];
            accv = __builtin_amdgcn_mfma_f32_16x16x32_f16(ao[ks], bwv.v, accv, 0, 0, 0);
            acct = __builtin_amdgcn_mfma_f32_16x16x32_f16(ao[ks], bwt.v, acct, 0, 0, 0);
        }
        int c = nt * 16 + (lane & 15);
        float biasv = bv[c], biast = bt[c];
#pragma unroll
        for (int r = 0; r < 4; r++) {
            int lrow = wave * 16 + (lane >> 4) * 4 + r;
            int gn = nb + lrow;
            if (gn < NN) {
                vis[(size_t)gn * HD + c] = fmaxf(accv[r] + biasv, 0.f);
                txt[(size_t)gn * HD + c] = fmaxf(acct[r] + biast, 0.f);
            }
        }
    }
}

// ---------------- launch ----------------

extern "C" void kernel_launch(void* const* d_in, const int* in_sizes, int n_in,
                              void* d_out, int out_size, void* d_ws, size_t ws_size,
                              hipStream_t stream) {
    (void)in_sizes; (void)n_in; (void)out_size; (void)ws_size;

    const float* x    = (const float*)d_in[0];
    const int*   edge = (const int*)d_in[1];   // [2,E]: src then dst
    const float* W1   = (const float*)d_in[2];
    const float* b1   = (const float*)d_in[3];
    const float* cw   = (const float*)d_in[4]; // [8,128,128]
    const float* W2   = (const float*)d_in[5];
    const float* b2   = (const float*)d_in[6];
    const float* Wv   = (const float*)d_in[7];
    const float* bv   = (const float*)d_in[8];
    const float* Wt   = (const float*)d_in[9];
    const float* bt   = (const float*)d_in[10];

    const int* esrc = edge;
    const int* edst = edge + NE;

    // d_out regions: [0]=h7 (f16, 512B-strided) then `out`; [1]=h0(f16) then vis;
    // [2]=g ping-pong (2 x f16) then txt
    float* out0 = (float*)d_out;
    float* reg1 = out0 + (size_t)NN * HD;
    float* reg2 = reg1 + (size_t)NN * HD;

    __half* h0h = (__half*)reg1;
    __half* ga  = (__half*)reg2;
    __half* gb  = (__half*)((char*)reg2 + H16_BYTES);

    // workspace layout
    char* ws = (char*)d_ws;
    int*   deg_i = (int*)(ws + 0);          // N ints
    int*   fill  = (int*)(ws + 400000);     // N ints
    int*   rowp  = (int*)(ws + 800000);     // N+1 ints
    int*   bsums = (int*)(ws + 1200128);    // 128 ints
    int*   col   = (int*)(ws + 1200640);    // E ints
    float* dinv  = (float*)(ws + 5200640);  // N floats
    __half* wf   = (__half*)(ws + 5600640); // 11 * 128*128 halfs = 360448 B
    __half* w1f  = (__half*)(ws + 5961088); // 256*128 halfs = 65536 B

    hipMemsetAsync(ws, 0, 800000, stream);  // deg_i + fill

    k_deg<<<(NE + 255) / 256, 256, 0, stream>>>(edst, deg_i);
    k_dinv<<<(NN + 255) / 256, 256, 0, stream>>>(deg_i, dinv);
    k_scan1<<<NBLK_SCAN, 1024, 0, stream>>>(deg_i, rowp, bsums);
    k_scan2<<<1, 128, 0, stream>>>(bsums);
    k_scan3<<<NBLK_SCAN, 1024, 0, stream>>>(rowp, bsums);
    k_fill<<<(NE + 255) / 256, 256, 0, stream>>>(esrc, edst, rowp, fill, col);
    k_wfrag<<<11 * 16, 256, 0, stream>>>(cw, W2, Wv, Wt, wf);
    k_w1frag<<<32, 256, 0, stream>>>(W1, w1f);

    k_init<<<(NN + INPB - 1) / INPB, 256, 0, stream>>>(x, w1f, b1, dinv, h0h, ga);

    // layers 0..6: f16 ping-pong (l even: ga->gb, odd: gb->ga). After l=6, g in gb.
    for (int l = 0; l < 7; l++) {
        const __half* gi = (l & 1) ? gb : ga;
        __half*       go = (l & 1) ? ga : gb;
        k_layer<0><<<NN / NPB, 256, 0, stream>>>((const __half2*)gi, go,
                                                 (__half*)nullptr, (const __half2*)h0h,
                                                 dinv, rowp, col,
                                                 wf + (size_t)l * HD * HD);
    }
    // layer 7: gb -> f16 h (strided) in region0
    k_layer<1><<<NN / NPB, 256, 0, stream>>>((const __half2*)gb, (__half*)nullptr,
                                             (__half*)out0, (const __half2*)h0h,
                                             dinv, rowp, col,
                                             wf + (size_t)7 * HD * HD);

    k_final<<<(NN + FNPB - 1) / FNPB, 256, 0, stream>>>((const __half*)out0, wf,
                                                        b2, bv, bt,
                                                        out0, reg1, reg2);
}